// Round 2
// baseline (25391.934 us; speedup 1.0000x reference)
//
#include <hip/hip_runtime.h>
#include <math.h>

// Problem constants: N=4, L=S=4096, C=256, K=100, DT=96, NHEAD=8, D=32
// All inputs/outputs are FP32 (reference is pure float32).

// ---------------------------------------------------------------------------
// Batched GEMM: C[b] = alpha * A[b] @ B[b], row-major, optional relu,
// optional per-batch rowcount: tiles fully beyond rowcount write zeros (exact,
// since those A rows are zero by construction).
// BM=BN=64, BK=16, 256 threads, 4x4 microtile.
// ---------------------------------------------------------------------------
__global__ __launch_bounds__(256) void gemm_kernel(
    const float* __restrict__ A, const float* __restrict__ B, float* __restrict__ C,
    int M, int N, int Kd, long sA, long sB, long sC,
    const int* __restrict__ rowcount, int relu, float alpha)
{
  int b = blockIdx.z;
  const float* Ab = A + (long)b * sA;
  const float* Bb = B + (long)b * sB;
  float* Cb = C + (long)b * sC;
  int row0 = blockIdx.y * 64, col0 = blockIdx.x * 64;
  int t = threadIdx.x, tx = t & 15, ty = t >> 4;
  bool skip = false;
  if (rowcount && row0 >= rowcount[b]) skip = true;
  float acc[4][4] = {};
  __shared__ float As[16][64];
  __shared__ float Bs[16][64];
  if (!skip) {
    for (int k0 = 0; k0 < Kd; k0 += 16) {
      #pragma unroll
      for (int i = 0; i < 4; i++) {
        int idx = t + i * 256;
        int ar = idx >> 4, ak = idx & 15;
        int gr = row0 + ar;
        As[ak][ar] = (gr < M) ? Ab[(long)gr * Kd + k0 + ak] : 0.f;
      }
      #pragma unroll
      for (int i = 0; i < 4; i++) {
        int idx = t + i * 256;
        int bk = idx >> 6, bc = idx & 63;
        int gc = col0 + bc;
        Bs[bk][bc] = (gc < N) ? Bb[(long)(k0 + bk) * N + gc] : 0.f;
      }
      __syncthreads();
      #pragma unroll
      for (int kk = 0; kk < 16; kk++) {
        float a0[4], b0[4];
        #pragma unroll
        for (int i = 0; i < 4; i++) a0[i] = As[kk][ty * 4 + i];
        #pragma unroll
        for (int j = 0; j < 4; j++) b0[j] = Bs[kk][tx * 4 + j];
        #pragma unroll
        for (int i = 0; i < 4; i++)
          #pragma unroll
          for (int j = 0; j < 4; j++)
            acc[i][j] += a0[i] * b0[j];
      }
      __syncthreads();
    }
  }
  #pragma unroll
  for (int i = 0; i < 4; i++) {
    int gr = row0 + ty * 4 + i;
    if (gr >= M) continue;
    #pragma unroll
    for (int j = 0; j < 4; j++) {
      int gc = col0 + tx * 4 + j;
      if (gc >= N) continue;
      float v = skip ? 0.f : acc[i][j] * alpha;
      if (relu && v < 0.f) v = 0.f;
      Cb[(long)gr * N + gc] = v;
    }
  }
}

static void launch_gemm(hipStream_t st, const float* A, const float* B,
    float* C, int M, int N, int Kd, long sA, long sB, long sC,
    const int* rowcount, int relu, float alpha)
{
  dim3 g((N + 63) / 64, (M + 63) / 64, 4), b(256);
  gemm_kernel<<<g, b, 0, st>>>(A, B, C, M, N, Kd, sA, sB, sC, rowcount, relu, alpha);
}

// ---------------------------------------------------------------------------
// block-wide (256 threads) pair-sum reduce, result broadcast to all threads
// ---------------------------------------------------------------------------
__device__ __forceinline__ float2 blk_sum2_256(float a, float b)
{
  __shared__ float sa[4], sb[4];
  int lane = threadIdx.x & 63, w = threadIdx.x >> 6;
  #pragma unroll
  for (int off = 32; off > 0; off >>= 1) { a += __shfl_down(a, off, 64); b += __shfl_down(b, off, 64); }
  if (lane == 0) { sa[w] = a; sb[w] = b; }
  __syncthreads();
  float ra = sa[0] + sa[1] + sa[2] + sa[3];
  float rb = sb[0] + sb[1] + sb[2] + sb[3];
  __syncthreads();
  return make_float2(ra, rb);
}

// ---------------------------------------------------------------------------
// Elementwise / small kernels
// ---------------------------------------------------------------------------
__global__ void cvt_kernel(float* dst, const float* src, long n) {
  long i = (long)blockIdx.x * 256 + threadIdx.x;
  if (i < n) dst[i] = src[i];
}

__global__ void bcast_seeds_kernel(float* seeds, const float* st) {
  long i = (long)blockIdx.x * 256 + threadIdx.x;
  if (i < 4L * 25600) seeds[i] = st[i % 25600];
}

// elu(x)+1 (= x+1 if x>0 else exp(x)), then zero rows >= cnt[n]
__global__ void elu_mask_kernel(float* q, long total, int rows, const int* cnt) {
  long i = (long)blockIdx.x * 256 + threadIdx.x;
  if (i >= total) return;
  float v = q[i];
  v = (v > 0.f) ? (v + 1.f) : expf(v);
  if (cnt) {
    long r = i >> 8;
    int n = (int)(r / rows), rr = (int)(r % rows);
    if (rr >= cnt[n]) v = 0.f;
  }
  q[i] = v;
}

__global__ void maskrows_kernel(float* v, long total, int rows, const int* cnt) {
  long i = (long)blockIdx.x * 256 + threadIdx.x;
  if (i >= total) return;
  long r = i >> 8;
  int n = (int)(r / rows), rr = (int)(r % rows);
  if (rr >= cnt[n]) v[i] = 0.f;
}

// KV[n,h,d,e] += sum_s K[n,s,h,d]*V[n,s,h,e]/s_len ; Ksum[n,h,d] += sum_s K
__global__ __launch_bounds__(1024) void kv_kernel(
    const float* __restrict__ Kb, const float* __restrict__ Vb,
    float* __restrict__ KV, float* __restrict__ Ksum,
    int s_len, float inv_s, const int* __restrict__ cnt, int chunk)
{
  int n = blockIdx.x, h = blockIdx.y;
  int slim = cnt ? min(cnt[n], s_len) : s_len;
  int s0b = blockIdx.z * chunk;
  int send = min(s0b + chunk, slim);
  if (s0b >= send) return;
  __shared__ float Kt[32][33];
  __shared__ float Vt[32][33];
  int tx = threadIdx.x, ty = threadIdx.y;
  float acc = 0.f, ks = 0.f;
  for (int s0 = s0b; s0 < send; s0 += 32) {
    int sr = s0 + ty;
    float kvv = 0.f, vvv = 0.f;
    if (sr < send) {
      long base = ((long)n * s_len + sr) * 256 + h * 32 + tx;
      kvv = Kb[base]; vvv = Vb[base];
    }
    Kt[ty][tx] = kvv; Vt[ty][tx] = vvv;
    __syncthreads();
    #pragma unroll
    for (int j = 0; j < 32; j++) acc += Kt[j][ty] * Vt[j][tx];
    if (tx == 0) {
      #pragma unroll
      for (int j = 0; j < 32; j++) ks += Kt[j][ty];
    }
    __syncthreads();
  }
  atomicAdd(&KV[((n * 8 + h) * 32 + ty) * 32 + tx], acc * inv_s);
  if (tx == 0) atomicAdd(&Ksum[(n * 8 + h) * 32 + ty], ks);
}

// msg[n,l,h*32+e] = (sum_d Q*KV) * Z * s_len ; Z = 1/(Q.Ksum + 1e-6)
__global__ __launch_bounds__(256) void zmsg_kernel(
    const float* __restrict__ Q, const float* __restrict__ KV,
    const float* __restrict__ Ksum, float* __restrict__ msg, int l, float s_len)
{
  int n = blockIdx.x;
  int r0 = blockIdx.y * 8;
  int t = threadIdx.x;
  __shared__ float KVs[8192];
  __shared__ float QL[256];
  __shared__ float Zl[8];
  for (int i = t; i < 8192; i += 256) KVs[i] = KV[n * 8192 + i];
  float Ks = Ksum[n * 256 + t];
  __syncthreads();
  int h = t >> 5, e = t & 31;
  for (int rr = 0; rr < 8; rr++) {
    int row = r0 + rr;
    if (row >= l) break;
    long base = ((long)n * l + row) * 256;
    QL[t] = Q[base + t];
    __syncthreads();
    float p = QL[t] * Ks;
    #pragma unroll
    for (int off = 16; off > 0; off >>= 1) p += __shfl_down(p, off, 32);
    if (e == 0) Zl[h] = 1.f / (p + 1e-6f);
    __syncthreads();
    float acc = 0.f;
    const float* kvh = KVs + h * 1024;
    #pragma unroll
    for (int d = 0; d < 32; d++) acc += QL[h * 32 + d] * kvh[d * 32 + e];
    msg[base + t] = acc * Zl[h] * s_len;
    __syncthreads();
  }
}

// cat[row] = [x_row, LN(msg2_row)]
__global__ void ln_cat_kernel(float* cat, const float* x, const float* m2) {
  long row = blockIdx.x; int t = threadIdx.x;
  float v = m2[row * 256 + t];
  float2 r = blk_sum2_256(v, v * v);
  float mu = r.x * (1.f / 256.f);
  float var = r.y * (1.f / 256.f) - mu * mu;
  cat[row * 512 + t] = x[row * 256 + t];
  cat[row * 512 + 256 + t] = (v - mu) * rsqrtf(var + 1e-5f);
}

// x_row += LN(h2_row)
__global__ void add_ln_kernel(float* x, const float* h2) {
  long row = blockIdx.x; int t = threadIdx.x;
  float v = h2[row * 256 + t];
  float2 r = blk_sum2_256(v, v * v);
  float mu = r.x * (1.f / 256.f);
  float var = r.y * (1.f / 256.f) - mu * mu;
  x[row * 256 + t] += (v - mu) * rsqrtf(var + 1e-5f);
}

// ---------------- topic pipeline ----------------
__global__ void tm_build_kernel(const float* t0, const float* t1, float* tm) {
  int n = blockIdx.x, m = blockIdx.y, l = threadIdx.x;
  if (l >= 100) return;
  float acc = 0.f;
  for (int d = 0; d < 96; d++)
    acc += t0[(n * 96 + d) * 100 + m] * t1[(n * 96 + d) * 100 + l];
  tm[(n * 100 + m) * 100 + l] = floorf(acc * 0.0625f);
}

// stats over m (axis=1) for fixed (n,l)
__global__ void tm_colstats_kernel(const float* tm, float* cmax, float* csum) {
  int n = blockIdx.x, l = blockIdx.y, t = threadIdx.x;
  __shared__ float red[128];
  float v = (t < 100) ? tm[(n * 100 + t) * 100 + l] : -1e30f;
  red[t] = v; __syncthreads();
  for (int off = 64; off > 0; off >>= 1) { if (t < off) red[t] = fmaxf(red[t], red[t + off]); __syncthreads(); }
  float mx = red[0]; __syncthreads();
  float e = (t < 100) ? expf(v - mx) : 0.f;
  red[t] = e; __syncthreads();
  for (int off = 64; off > 0; off >>= 1) { if (t < off) red[t] += red[t + off]; __syncthreads(); }
  if (t == 0) { cmax[n * 100 + l] = mx; csum[n * 100 + l] = red[0]; }
}

// stats over l (axis=2) for fixed (n,m)
__global__ void tm_rowstats_kernel(const float* tm, float* rmax, float* rsum) {
  int n = blockIdx.x, m = blockIdx.y, t = threadIdx.x;
  __shared__ float red[128];
  float v = (t < 100) ? tm[(n * 100 + m) * 100 + t] : -1e30f;
  red[t] = v; __syncthreads();
  for (int off = 64; off > 0; off >>= 1) { if (t < off) red[t] = fmaxf(red[t], red[t + off]); __syncthreads(); }
  float mx = red[0]; __syncthreads();
  float e = (t < 100) ? expf(v - mx) : 0.f;
  red[t] = e; __syncthreads();
  for (int off = 64; off > 0; off >>= 1) { if (t < off) red[t] += red[t + off]; __syncthreads(); }
  if (t == 0) { rmax[n * 100 + m] = mx; rsum[n * 100 + m] = red[0]; }
}

__global__ void tm_argmax_kernel(const float* tm, const float* cmax, const float* csum,
                                 const float* rmax, const float* rsum, int* tmidx) {
  int n = blockIdx.x, m = blockIdx.y, t = threadIdx.x;
  __shared__ float rv[128]; __shared__ int ri[128];
  float v = -1e30f;
  if (t < 100) {
    float x = tm[(n * 100 + m) * 100 + t];
    v = (expf(x - cmax[n * 100 + t]) / csum[n * 100 + t]) * (expf(x - rmax[n * 100 + m]) / rsum[n * 100 + m]);
  }
  rv[t] = v; ri[t] = t; __syncthreads();
  for (int off = 64; off > 0; off >>= 1) {
    if (t < off) {
      if (rv[t + off] > rv[t] || (rv[t + off] == rv[t] && ri[t + off] < ri[t])) { rv[t] = rv[t + off]; ri[t] = ri[t + off]; }
    }
    __syncthreads();
  }
  if (t == 0) tmidx[n * 100 + m] = ri[0];
}

// pooled (192->96) concat topic, gather t1 with tmidx of batch 3
__global__ void topicp_kernel(const float* t0raw, const float* t1raw, const int* tmidx, float* topicp) {
  int n = blockIdx.x, m = blockIdx.y, j = threadIdx.x;
  if (j >= 96) return;
  int g = tmidx[300 + m];
  float a, b;
  if (j < 48) {
    a = t0raw[(n * 96 + 2 * j) * 100 + m];
    b = t0raw[(n * 96 + 2 * j + 1) * 100 + m];
  } else {
    int d0 = 2 * j - 96;
    a = t1raw[(n * 96 + d0) * 100 + g];
    b = t1raw[(n * 96 + d0 + 1) * 100 + g];
  }
  topicp[(n * 100 + m) * 96 + j] = 0.5f * (a + b);
}

// pool seeds 256->160, concat topicp, layernorm(256)
__global__ void seedsF_kernel(const float* seeds, const float* topicp, float* seedsF) {
  int n = blockIdx.x, k = blockIdx.y, t = threadIdx.x;
  float v;
  if (t < 160) {
    int s = (t * 256) / 160;
    int e = ((t + 1) * 256 + 159) / 160;
    float a = 0.f;
    for (int i = s; i < e; i++) a += seeds[(n * 100 + k) * 256 + i];
    v = a / (float)(e - s);
  } else {
    v = topicp[(n * 100 + k) * 96 + (t - 160)];
  }
  float2 r = blk_sum2_256(v, v * v);
  float mu = r.x * (1.f / 256.f);
  float var = r.y * (1.f / 256.f) - mu * mu;
  seedsF[(n * 100 + k) * 256 + t] = (v - mu) * rsqrtf(var + 1e-5f);
}

__global__ void transpose_seeds_kernel(const float* sF, float* sT) {
  long i = (long)blockIdx.x * 256 + threadIdx.x;
  if (i >= 4L * 25600) return;
  int n = (int)(i / 25600); int r = (int)(i % 25600); int k = r / 256; int d = r % 256;
  sT[n * 25600 + d * 100 + k] = sF[i];
}

// ---------------- dmatrix post-processing ----------------
__global__ void softmax_rows_kernel(const float* dm, float* prob) {
  long row = blockIdx.x; int t = threadIdx.x;
  __shared__ float red[128];
  float v = (t < 100) ? dm[row * 100 + t] : -1e30f;
  red[t] = v; __syncthreads();
  for (int off = 64; off > 0; off >>= 1) { if (t < off) red[t] = fmaxf(red[t], red[t + off]); __syncthreads(); }
  float mx = red[0]; __syncthreads();
  float e = (t < 100) ? expf(v - mx) : 0.f;
  red[t] = e; __syncthreads();
  for (int off = 64; off > 0; off >>= 1) { if (t < off) red[t] += red[t + off]; __syncthreads(); }
  float s = red[0];
  if (t < 100) prob[row * 100 + t] = e / s;
}

__global__ void colsum_kernel(const float* prob, float* cs0, float* cs1) {
  int k = blockIdx.x, n = blockIdx.y, half = blockIdx.z;
  int t = threadIdx.x;
  const float* p = prob + ((long)n * 8192 + half * 4096) * 100 + k;
  float s = 0.f;
  for (int m = t; m < 4096; m += 256) s += p[(long)m * 100];
  float2 r = blk_sum2_256(s, 0.f);
  if (t == 0) (half ? cs1 : cs0)[n * 100 + k] = r.x;
}

__global__ void topk_kernel(const float* cs0, const float* cs1, int* inds) {
  int n = blockIdx.x, t = threadIdx.x;
  __shared__ float rv[128]; __shared__ int ri[128]; __shared__ int sbest;
  float base = (t < 100) ? cs0[n * 100 + t] * cs1[n * 100 + t] : -1.f;
  for (int kk = 0; kk < 6; kk++) {
    rv[t] = base; ri[t] = t; __syncthreads();
    for (int off = 64; off > 0; off >>= 1) {
      if (t < off) {
        if (rv[t + off] > rv[t] || (rv[t + off] == rv[t] && ri[t + off] < ri[t])) { rv[t] = rv[t + off]; ri[t] = ri[t + off]; }
      }
      __syncthreads();
    }
    if (t == 0) { inds[n * 6 + kk] = ri[0]; sbest = ri[0]; }
    __syncthreads();
    if (t == sbest) base = -1.f;
    __syncthreads();
  }
}

__global__ void argmax_rows_kernel(const float* dm, int* amax) {
  int row = blockIdx.x * 256 + threadIdx.x;
  if (row >= 32768) return;
  const float* p = dm + (long)row * 100;
  float best = p[0]; int bi = 0;
  for (int k = 1; k < 100; k++) { float v = p[k]; if (v > best) { best = v; bi = k; } }
  amax[row] = bi;
}

// ---------------- sample loop ----------------
// stable partition: selected indices (ascending) first, then unselected
__global__ __launch_bounds__(1024) void build_ord_kernel(
    const int* amax, const int* inds, int kk, int* ord0, int* ord1, int* cnt0, int* cnt1)
{
  int n = blockIdx.x, half = blockIdx.y;
  int t = threadIdx.x;
  __shared__ int ts[1024];
  int target = inds[n * 6 + kk];
  const int* am = amax + n * 8192 + half * 4096;
  int f[4]; int lc = 0;
  #pragma unroll
  for (int j = 0; j < 4; j++) { f[j] = (am[t * 4 + j] == target) ? 1 : 0; lc += f[j]; }
  ts[t] = lc; __syncthreads();
  for (int off = 1; off < 1024; off <<= 1) {
    int add = (t >= off) ? ts[t - off] : 0;
    __syncthreads();
    ts[t] += add;
    __syncthreads();
  }
  int total = ts[1023];
  int run = (t == 0) ? 0 : ts[t - 1];
  int* ord = (half ? ord1 : ord0) + n * 4096;
  #pragma unroll
  for (int j = 0; j < 4; j++) {
    int i = t * 4 + j;
    if (f[j]) { ord[run] = i; run++; }
    else { ord[total + (i - run)] = i; }
  }
  if (t == 0) (half ? cnt1 : cnt0)[n] = total;
}

__global__ void cond_kernel(const int* c0, const int* c1, float* condf) {
  int a = c0[0] + c0[1] + c0[2] + c0[3];
  int b = c1[0] + c1[1] + c1[2] + c1[3];
  condf[0] = (a > 0 && b > 0) ? 1.f : 0.f;
}

__global__ void gather_kernel(float* nf, const float* fcur, const int* ord, const int* cnt) {
  int n = blockIdx.y;
  long i = (long)blockIdx.x * 256 + threadIdx.x;
  int r = (int)(i >> 8), c = (int)(i & 255);
  float v = 0.f;
  if (r < cnt[n]) v = fcur[((long)n * 4096 + ord[n * 4096 + r]) * 256 + c];
  nf[(long)n * 1048576 + i] = v;
}

__global__ void scatter_kernel(float* up, const float* nf, const int* ord, const int* cnt, const float* condf) {
  int n = blockIdx.y;
  long i = (long)blockIdx.x * 256 + threadIdx.x;
  int r = (int)(i >> 8), c = (int)(i & 255);
  if (r < cnt[n]) {
    up[((long)n * 4096 + ord[n * 4096 + r]) * 256 + c] += nf[(long)n * 1048576 + i] * condf[0];
  }
}

__global__ void final_mix_kernel(const float* fcur, const float* up, const int* amax,
                                 const int* inds, float* out, int half) {
  int n = blockIdx.y;
  long i = (long)blockIdx.x * 256 + threadIdx.x;
  int l = (int)(i >> 8);
  int a = amax[n * 8192 + half * 4096 + l];
  const int* in_ = inds + n * 6;
  bool member = (a == in_[0]) | (a == in_[1]) | (a == in_[2]) | (a == in_[3]) | (a == in_[4]) | (a == in_[5]);
  long idx = (long)n * 1048576 + i;
  float res = (member ? 0.f : 1.f) * fcur[idx] + up[idx];
  out[(long)half * 4194304 + idx] = res;
}

// tmi = dm * 3x3-neighborhood-mean of raw-reshaped dm (zero pad, /9)
__global__ void tmi_kernel(const float* dmat, float* out) {
  int n = blockIdx.y, half = blockIdx.z;
  long i = (long)blockIdx.x * 256 + threadIdx.x;  // < 409600
  const float* dm = dmat + (long)n * 819200 + (long)half * 409600;
  int a = (int)(i / 100), b = (int)(i % 100);
  int y = a >> 6, x = a & 63;
  float sum = 0.f;
  for (int dy = -1; dy <= 1; dy++) {
    int yy = y + dy; if (yy < 0 || yy >= 64) continue;
    for (int dx = -1; dx <= 1; dx++) {
      int xc = x + dx; if (xc < 0 || xc >= 64) continue;
      sum += dm[b * 4096 + yy * 64 + xc];
    }
  }
  float val = dm[i] * (sum * (1.f / 9.f));
  out[8388608L + (long)half * 1638400 + (long)n * 409600 + i] = val;
}

// ---------------------------------------------------------------------------
struct Seg { const float* p; int rows; long bstride; };

extern "C" void kernel_launch(void* const* d_in, const int* in_sizes, int n_in,
                              void* d_out, int out_size, void* d_ws, size_t ws_size,
                              hipStream_t stream)
{
  (void)in_sizes; (void)n_in; (void)out_size; (void)ws_size;
  const float* feat0_in = (const float*)d_in[0];
  const float* feat1_in = (const float*)d_in[1];
  const float* topic0 = (const float*)d_in[2];
  const float* topic1 = (const float*)d_in[3];
  const float* seed_tokens = (const float*)d_in[4];
  const float* Wq = (const float*)d_in[5];
  const float* Wk = (const float*)d_in[6];
  const float* Wv = (const float*)d_in[7];
  const float* Wm = (const float*)d_in[8];
  const float* W1 = (const float*)d_in[9];
  const float* W2 = (const float*)d_in[10];
  float* out = (float*)d_out;

  float* base = (float*)d_ws;
  long off = 0;
  auto alloc = [&](long n) -> float* { float* p = base + off; off += (n + 255) & ~255L; return p; };
  float* f0    = alloc(4194304);   // feat0 current
  float* f1    = alloc(4194304);
  float* qb    = alloc(4194304);   // Q / h2
  float* kb    = alloc(8388608);   // K / msg / cat / prob
  float* vb    = alloc(8388608);   // V / msg2 / h1
  float* seeds = alloc(102400);
  float* kvks  = alloc(33792);     // KV (32768) + Ksum (1024)
  float* dmat  = alloc(3276800);
  float* nf0   = alloc(4194304);
  float* nf1   = alloc(4194304);
  float* up0   = alloc(4194304);
  float* up1   = alloc(4194304);
  float* tmb   = alloc(40000);
  float* cmaxb = alloc(400); float* csumb = alloc(400);
  float* rmaxb = alloc(400); float* rsumb = alloc(400);
  float* topicp= alloc(38400);
  float* sF    = alloc(102400);
  float* sT    = alloc(102400);
  float* cs0   = alloc(400);
  float* cs1   = alloc(400);
  float* condf = alloc(256);
  int* tmidx = (int*)alloc(400);
  int* amax  = (int*)alloc(32768);
  int* inds  = (int*)alloc(256);
  int* cnt0  = (int*)alloc(256);
  int* cnt1  = (int*)alloc(256);
  int* ord0  = (int*)alloc(16384);
  int* ord1  = (int*)alloc(16384);

  // enc layer: x (fp32, in-place update), source = up to 2 segments
  auto enc = [&](float* x, int l, Seg s0, Seg s1, int layer, const int* xc, const int* sc) {
    int s_len = s0.rows + s1.rows;
    const float* wq = Wq + (long)layer * 65536;
    const float* wk = Wk + (long)layer * 65536;
    const float* wv = Wv + (long)layer * 65536;
    const float* wm = Wm + (long)layer * 65536;
    const float* w1 = W1 + (long)layer * 262144;
    const float* w2 = W2 + (long)layer * 131072;
    // q = x @ Wq ; Q = elu(q)+1, masked  -> qb
    launch_gemm(stream, x, wq, qb, l, 256, 256, (long)l * 256, 0, (long)l * 256, xc, 0, 1.f);
    { long tot = 4L * l * 256; elu_mask_kernel<<<(int)((tot + 255) / 256), 256, 0, stream>>>(qb, tot, l, xc); }
    // k -> kb, v -> vb from source segments
    long roff = 0;
    Seg ss[2] = { s0, s1 };
    for (int i = 0; i < 2; i++) {
      if (ss[i].rows <= 0) continue;
      launch_gemm(stream, ss[i].p, wk, kb + roff * 256, ss[i].rows, 256, 256, ss[i].bstride, 0, (long)s_len * 256, sc, 0, 1.f);
      launch_gemm(stream, ss[i].p, wv, vb + roff * 256, ss[i].rows, 256, 256, ss[i].bstride, 0, (long)s_len * 256, sc, 0, 1.f);
      roff += ss[i].rows;
    }
    { long tot = 4L * s_len * 256;
      elu_mask_kernel<<<(int)((tot + 255) / 256), 256, 0, stream>>>(kb, tot, s_len, sc);
      if (sc) maskrows_kernel<<<(int)((tot + 255) / 256), 256, 0, stream>>>(vb, tot, s_len, sc); }
    // KV, Ksum
    hipMemsetAsync(kvks, 0, 33792 * sizeof(float), stream);
    int nch = (s_len + 1023) / 1024;
    kv_kernel<<<dim3(4, 8, nch), dim3(32, 32), 0, stream>>>(kb, vb, kvks, kvks + 32768, s_len, 1.f / (float)s_len, sc, 1024);
    // msg (fused Z) -> kb  (K dead after kv)
    zmsg_kernel<<<dim3(4, (l + 7) / 8), 256, 0, stream>>>(qb, kvks, kvks + 32768, kb, l, (float)s_len);
    // msg2 = msg @ Wm -> vb  (V dead)
    launch_gemm(stream, kb, wm, vb, l, 256, 256, (long)l * 256, 0, (long)l * 256, xc, 0, 1.f);
    // cat = [x, LN(msg2)] -> kb  (msg dead)
    ln_cat_kernel<<<4 * l, 256, 0, stream>>>(kb, x, vb);
    // h1 = relu(cat @ W1) -> vb  (msg2 dead)
    launch_gemm(stream, kb, w1, vb, l, 512, 512, (long)l * 512, 0, (long)l * 512, xc, 1, 1.f);
    // h2 = h1 @ W2 -> qb  (Q dead)
    launch_gemm(stream, vb, w2, qb, l, 256, 512, (long)l * 512, 0, (long)l * 256, xc, 0, 1.f);
    // x += LN(h2)
    add_ln_kernel<<<4 * l, 256, 0, stream>>>(x, qb);
  };

  // ---- init ----
  cvt_kernel<<<16384, 256, 0, stream>>>(f0, feat0_in, 4194304);
  cvt_kernel<<<16384, 256, 0, stream>>>(f1, feat1_in, 4194304);
  bcast_seeds_kernel<<<400, 256, 0, stream>>>(seeds, seed_tokens);

  // ---- topic pipeline ----
  tm_build_kernel<<<dim3(4, 100), 128, 0, stream>>>(topic0, topic1, tmb);
  tm_colstats_kernel<<<dim3(4, 100), 128, 0, stream>>>(tmb, cmaxb, csumb);
  tm_rowstats_kernel<<<dim3(4, 100), 128, 0, stream>>>(tmb, rmaxb, rsumb);
  tm_argmax_kernel<<<dim3(4, 100), 128, 0, stream>>>(tmb, cmaxb, csumb, rmaxb, rsumb, tmidx);
  topicp_kernel<<<dim3(4, 100), 128, 0, stream>>>(topic0, topic1, tmidx, topicp);

  // ---- main encoder layers (feat source = ORIGINAL feat0|feat1 concat) ----
  Seg segF0{ feat0_in, 4096, 1048576 };
  Seg segF1{ feat1_in, 4096, 1048576 };
  Seg segSeeds{ seeds, 100, 25600 };
  Seg segNone{ nullptr, 0, 0 };
  enc(seeds, 100, segF0, segF1, 0, nullptr, nullptr);
  enc(f0, 4096, segSeeds, segNone, 1, nullptr, nullptr);
  enc(f1, 4096, segSeeds, segNone, 1, nullptr, nullptr);
  enc(seeds, 100, segF0, segF1, 2, nullptr, nullptr);
  enc(f0, 4096, segSeeds, segNone, 3, nullptr, nullptr);
  enc(f1, 4096, segSeeds, segNone, 3, nullptr, nullptr);

  // ---- seeds final + dmatrix ----
  seedsF_kernel<<<dim3(4, 100), 256, 0, stream>>>(seeds, topicp, sF);
  transpose_seeds_kernel<<<400, 256, 0, stream>>>(sF, sT);
  launch_gemm(stream, feat0_in, sT, dmat, 4096, 100, 256, 1048576, 25600, 819200, nullptr, 0, 0.0625f);
  launch_gemm(stream, feat1_in, sT, dmat + 409600, 4096, 100, 256, 1048576, 25600, 819200, nullptr, 0, 0.0625f);

  float* prob = kb;  // reuse
  softmax_rows_kernel<<<32768, 128, 0, stream>>>(dmat, prob);
  colsum_kernel<<<dim3(100, 4, 2), 256, 0, stream>>>(prob, cs0, cs1);
  topk_kernel<<<4, 128, 0, stream>>>(cs0, cs1, inds);
  argmax_rows_kernel<<<128, 256, 0, stream>>>(dmat, amax);

  hipMemsetAsync(up0, 0, 4194304 * sizeof(float), stream);
  hipMemsetAsync(up1, 0, 4194304 * sizeof(float), stream);

  // ---- sample loop ----
  for (int kk = 0; kk < 6; kk++) {
    build_ord_kernel<<<dim3(4, 2), 1024, 0, stream>>>(amax, inds, kk, ord0, ord1, cnt0, cnt1);
    cond_kernel<<<1, 1, 0, stream>>>(cnt0, cnt1, condf);
    gather_kernel<<<dim3(4096, 4), 256, 0, stream>>>(nf0, f0, ord0, cnt0);
    gather_kernel<<<dim3(4096, 4), 256, 0, stream>>>(nf1, f1, ord1, cnt1);
    Seg sN0{ nf0, 4096, 1048576 };
    Seg sN1{ nf1, 4096, 1048576 };
    for (int idt = 0; idt < 2; idt++) {
      int wA = 4 + idt * 2, wB = wA + 1;
      enc(nf0, 4096, sN0, segNone, wA, cnt0, cnt0);
      enc(nf1, 4096, sN1, segNone, wA, cnt1, cnt1);
      enc(nf0, 4096, sN1, segNone, wB, cnt0, cnt1);
      enc(nf1, 4096, sN0, segNone, wB, cnt1, cnt0);
    }
    scatter_kernel<<<dim3(4096, 4), 256, 0, stream>>>(up0, nf0, ord0, cnt0, condf);
    scatter_kernel<<<dim3(4096, 4), 256, 0, stream>>>(up1, nf1, ord1, cnt1, condf);
  }

  // ---- outputs ----
  final_mix_kernel<<<dim3(4096, 4), 256, 0, stream>>>(f0, up0, amax, inds, out, 0);
  final_mix_kernel<<<dim3(4096, 4), 256, 0, stream>>>(f1, up1, amax, inds, out, 1);
  tmi_kernel<<<dim3(1600, 4, 2), 256, 0, stream>>>(dmat, out);
}

// Round 3
// 23502.016 us; speedup vs baseline: 1.0804x; 1.0804x over previous
//
#include <hip/hip_runtime.h>
#include <math.h>

// Problem constants: N=4, L=S=4096, C=256, K=100, DT=96, NHEAD=8, D=32
// All inputs/outputs FP32. Big GEMMs use bf16x3 split-precision MFMA
// (a_hi*b_hi + a_hi*b_lo + a_lo*b_hi with fp32 accumulate ~= fp32 fidelity).

typedef __attribute__((ext_vector_type(8))) short  frag8;   // 8 bf16 (4 VGPRs)
typedef __attribute__((ext_vector_type(4))) float  f32x4;

__device__ __forceinline__ short f2bf(float f) {
  unsigned u = __float_as_uint(f);
  unsigned r = (u + 0x7FFFu + ((u >> 16) & 1u)) >> 16;
  return (short)r;
}
__device__ __forceinline__ float bf2f(short s) {
  return __uint_as_float(((unsigned)(unsigned short)s) << 16);
}

// ---------------------------------------------------------------------------
// Batched MFMA GEMM: C[b] = alpha * act(A[b] @ B[b]), row-major.
// mode: 0 none, 1 relu, 2 elu(x)+1.  rowcount: rows >= cnt[b] write 0
// (exact: those A rows are zero / masked in the reference).
// Tile 128x128, BK=32, 256 threads = 4 waves in 2x2, each wave 64x64 via
// 16 tiles of v_mfma_f32_16x16x32_bf16, 3 MFMA per tile (bf16x3).
// Layouts (verified m89/m120): A/B frag [idx=lane&15][k=(lane>>4)*8+j];
// C/D col=lane&15, row=(lane>>4)*4+reg.
// ---------------------------------------------------------------------------
__global__ __launch_bounds__(256) void gemm_mfma_kernel(
    const float* __restrict__ A, const float* __restrict__ B, float* __restrict__ C,
    int M, int N, int Kd, long sA, long sB, long sC,
    const int* __restrict__ rowcount, int mode, float alpha)
{
  int b = blockIdx.z;
  const float* Ab = A + (long)b * sA;
  const float* Bb = B + (long)b * sB;
  float* Cb = C + (long)b * sC;
  int row0 = blockIdx.y * 128, col0 = blockIdx.x * 128;
  int cntb = rowcount ? rowcount[b] : M;
  int t = threadIdx.x;
  int lane = t & 63, wid = t >> 6;
  int wm = wid >> 1, wn = wid & 1;
  int fi = lane & 15;          // frag row/col index
  int fq = lane >> 4;          // quad -> k offset = fq*8
  bool skip = row0 >= cntb;

  // +8 bf16 pad (stride 40 shorts = 80 B): frag b128 reads alias max 2-way (free)
  __shared__ __align__(16) short Ah[128][40];
  __shared__ __align__(16) short Al[128][40];
  __shared__ __align__(16) short Bh[128][40];
  __shared__ __align__(16) short Bl[128][40];

  f32x4 acc[4][4];
  #pragma unroll
  for (int i = 0; i < 4; i++)
    #pragma unroll
    for (int j = 0; j < 4; j++)
      acc[i][j] = (f32x4){0.f, 0.f, 0.f, 0.f};

  if (!skip) {
    int tr = t >> 3;            // 0..31 (A stage row)
    int tc = (t & 7) * 4;       // 0..28 (A stage k)
    int bn = (t & 31) * 4;      // 0..124 (B stage col)
    int bk = t >> 5;            // 0..7  (B stage k)
    for (int k0 = 0; k0 < Kd; k0 += 32) {
      // stage A: 128 x 32 fp32 -> hi/lo bf16
      #pragma unroll
      for (int p = 0; p < 4; p++) {
        int r = tr + p * 32;
        int gr = row0 + r;
        float4 v = make_float4(0.f, 0.f, 0.f, 0.f);
        if (gr < M) v = *(const float4*)&Ab[(long)gr * Kd + k0 + tc];
        float vv[4] = {v.x, v.y, v.z, v.w};
        #pragma unroll
        for (int e = 0; e < 4; e++) {
          short h = f2bf(vv[e]);
          Ah[r][tc + e] = h;
          Al[r][tc + e] = f2bf(vv[e] - bf2f(h));
        }
      }
      // stage B transposed: Bs[n][k]
      #pragma unroll
      for (int p = 0; p < 4; p++) {
        int kk = bk + p * 8;
        long gkN = (long)(k0 + kk) * N;
        #pragma unroll
        for (int e = 0; e < 4; e++) {
          int gc = col0 + bn + e;
          float v = (gc < N) ? Bb[gkN + gc] : 0.f;
          short h = f2bf(v);
          Bh[bn + e][kk] = h;
          Bl[bn + e][kk] = f2bf(v - bf2f(h));
        }
      }
      __syncthreads();
      frag8 ah[4], al[4], bh[4], bl[4];
      #pragma unroll
      for (int i = 0; i < 4; i++) {
        ah[i] = *(const frag8*)&Ah[wm * 64 + i * 16 + fi][fq * 8];
        al[i] = *(const frag8*)&Al[wm * 64 + i * 16 + fi][fq * 8];
      }
      #pragma unroll
      for (int j = 0; j < 4; j++) {
        bh[j] = *(const frag8*)&Bh[wn * 64 + j * 16 + fi][fq * 8];
        bl[j] = *(const frag8*)&Bl[wn * 64 + j * 16 + fi][fq * 8];
      }
      #pragma unroll
      for (int i = 0; i < 4; i++)
        #pragma unroll
        for (int j = 0; j < 4; j++) {
          acc[i][j] = __builtin_amdgcn_mfma_f32_16x16x32_bf16(ah[i], bh[j], acc[i][j], 0, 0, 0);
          acc[i][j] = __builtin_amdgcn_mfma_f32_16x16x32_bf16(ah[i], bl[j], acc[i][j], 0, 0, 0);
          acc[i][j] = __builtin_amdgcn_mfma_f32_16x16x32_bf16(al[i], bh[j], acc[i][j], 0, 0, 0);
        }
      __syncthreads();
    }
  }
  // epilogue
  #pragma unroll
  for (int i = 0; i < 4; i++) {
    #pragma unroll
    for (int reg = 0; reg < 4; reg++) {
      int gr = row0 + wm * 64 + i * 16 + fq * 4 + reg;
      if (gr >= M) continue;
      bool zero = skip || (rowcount && gr >= cntb);
      #pragma unroll
      for (int j = 0; j < 4; j++) {
        int gc = col0 + wn * 64 + j * 16 + fi;
        if (gc >= N) continue;
        float v;
        if (zero) v = 0.f;
        else {
          v = acc[i][j][reg] * alpha;
          if (mode == 1) { if (v < 0.f) v = 0.f; }
          else if (mode == 2) { v = (v > 0.f) ? (v + 1.f) : expf(v); }
        }
        Cb[(long)gr * N + gc] = v;
      }
    }
  }
}

static void launch_gemm(hipStream_t st, const float* A, const float* B,
    float* C, int M, int N, int Kd, long sA, long sB, long sC,
    const int* rowcount, int mode, float alpha)
{
  dim3 g((N + 127) / 128, (M + 127) / 128, 4), b(256);
  gemm_mfma_kernel<<<g, b, 0, st>>>(A, B, C, M, N, Kd, sA, sB, sC, rowcount, mode, alpha);
}

// ---------------------------------------------------------------------------
__device__ __forceinline__ float2 blk_sum2_256(float a, float b)
{
  __shared__ float sa[4], sb[4];
  int lane = threadIdx.x & 63, w = threadIdx.x >> 6;
  #pragma unroll
  for (int off = 32; off > 0; off >>= 1) { a += __shfl_down(a, off, 64); b += __shfl_down(b, off, 64); }
  if (lane == 0) { sa[w] = a; sb[w] = b; }
  __syncthreads();
  float ra = sa[0] + sa[1] + sa[2] + sa[3];
  float rb = sb[0] + sb[1] + sb[2] + sb[3];
  __syncthreads();
  return make_float2(ra, rb);
}

__global__ void cvt_kernel(float* dst, const float* src, long n) {
  long i = (long)blockIdx.x * 256 + threadIdx.x;
  if (i < n) dst[i] = src[i];
}

__global__ void bcast_seeds_kernel(float* seeds, const float* st) {
  long i = (long)blockIdx.x * 256 + threadIdx.x;
  if (i < 4L * 25600) seeds[i] = st[i % 25600];
}

// KV[n,h,d,e] += sum_s K[n,s,h,d]*V[n,s,h,e]/s_len ; Ksum[n,h,d] += sum_s K
__global__ __launch_bounds__(1024) void kv_kernel(
    const float* __restrict__ Kb, const float* __restrict__ Vb,
    float* __restrict__ KV, float* __restrict__ Ksum,
    int s_len, float inv_s, const int* __restrict__ cnt, int chunk)
{
  int n = blockIdx.x, h = blockIdx.y;
  int slim = cnt ? min(cnt[n], s_len) : s_len;
  int s0b = blockIdx.z * chunk;
  int send = min(s0b + chunk, slim);
  if (s0b >= send) return;
  __shared__ float Kt[32][33];
  __shared__ float Vt[32][33];
  int tx = threadIdx.x, ty = threadIdx.y;
  float acc = 0.f, ks = 0.f;
  for (int s0 = s0b; s0 < send; s0 += 32) {
    int sr = s0 + ty;
    float kvv = 0.f, vvv = 0.f;
    if (sr < send) {
      long base = ((long)n * s_len + sr) * 256 + h * 32 + tx;
      kvv = Kb[base]; vvv = Vb[base];
    }
    Kt[ty][tx] = kvv; Vt[ty][tx] = vvv;
    __syncthreads();
    #pragma unroll
    for (int j = 0; j < 32; j++) acc += Kt[j][ty] * Vt[j][tx];
    if (tx == 0) {
      #pragma unroll
      for (int j = 0; j < 32; j++) ks += Kt[j][ty];
    }
    __syncthreads();
  }
  atomicAdd(&KV[((n * 8 + h) * 32 + ty) * 32 + tx], acc * inv_s);
  if (tx == 0) atomicAdd(&Ksum[(n * 8 + h) * 32 + ty], ks);
}

// msg[n,l,h*32+e] = (sum_d Q*KV) * Z * s_len ; Z = 1/(Q.Ksum + 1e-6)
__global__ __launch_bounds__(256) void zmsg_kernel(
    const float* __restrict__ Q, const float* __restrict__ KV,
    const float* __restrict__ Ksum, float* __restrict__ msg, int l, float s_len)
{
  int n = blockIdx.x;
  int r0 = blockIdx.y * 8;
  int t = threadIdx.x;
  __shared__ float KVs[8192];
  __shared__ float QL[256];
  __shared__ float Zl[8];
  for (int i = t; i < 8192; i += 256) KVs[i] = KV[n * 8192 + i];
  float Ks = Ksum[n * 256 + t];
  __syncthreads();
  int h = t >> 5, e = t & 31;
  for (int rr = 0; rr < 8; rr++) {
    int row = r0 + rr;
    if (row >= l) break;
    long base = ((long)n * l + row) * 256;
    QL[t] = Q[base + t];
    __syncthreads();
    float p = QL[t] * Ks;
    #pragma unroll
    for (int off = 16; off > 0; off >>= 1) p += __shfl_down(p, off, 32);
    if (e == 0) Zl[h] = 1.f / (p + 1e-6f);
    __syncthreads();
    float acc = 0.f;
    const float* kvh = KVs + h * 1024;
    #pragma unroll
    for (int d = 0; d < 32; d++) acc += QL[h * 32 + d] * kvh[d * 32 + e];
    msg[base + t] = acc * Zl[h] * s_len;
    __syncthreads();
  }
}

// cat[row] = [x_row, LN(msg2_row)]
__global__ void ln_cat_kernel(float* cat, const float* x, const float* m2) {
  long row = blockIdx.x; int t = threadIdx.x;
  float v = m2[row * 256 + t];
  float2 r = blk_sum2_256(v, v * v);
  float mu = r.x * (1.f / 256.f);
  float var = r.y * (1.f / 256.f) - mu * mu;
  cat[row * 512 + t] = x[row * 256 + t];
  cat[row * 512 + 256 + t] = (v - mu) * rsqrtf(var + 1e-5f);
}

// x_row += LN(h2_row)
__global__ void add_ln_kernel(float* x, const float* h2) {
  long row = blockIdx.x; int t = threadIdx.x;
  float v = h2[row * 256 + t];
  float2 r = blk_sum2_256(v, v * v);
  float mu = r.x * (1.f / 256.f);
  float var = r.y * (1.f / 256.f) - mu * mu;
  x[row * 256 + t] += (v - mu) * rsqrtf(var + 1e-5f);
}

// ---------------- topic pipeline ----------------
__global__ void tm_build_kernel(const float* t0, const float* t1, float* tm) {
  int n = blockIdx.x, m = blockIdx.y, l = threadIdx.x;
  if (l >= 100) return;
  float acc = 0.f;
  for (int d = 0; d < 96; d++)
    acc += t0[(n * 96 + d) * 100 + m] * t1[(n * 96 + d) * 100 + l];
  tm[(n * 100 + m) * 100 + l] = floorf(acc * 0.0625f);
}

__global__ void tm_colstats_kernel(const float* tm, float* cmax, float* csum) {
  int n = blockIdx.x, l = blockIdx.y, t = threadIdx.x;
  __shared__ float red[128];
  float v = (t < 100) ? tm[(n * 100 + t) * 100 + l] : -1e30f;
  red[t] = v; __syncthreads();
  for (int off = 64; off > 0; off >>= 1) { if (t < off) red[t] = fmaxf(red[t], red[t + off]); __syncthreads(); }
  float mx = red[0]; __syncthreads();
  float e = (t < 100) ? expf(v - mx) : 0.f;
  red[t] = e; __syncthreads();
  for (int off = 64; off > 0; off >>= 1) { if (t < off) red[t] += red[t + off]; __syncthreads(); }
  if (t == 0) { cmax[n * 100 + l] = mx; csum[n * 100 + l] = red[0]; }
}

__global__ void tm_rowstats_kernel(const float* tm, float* rmax, float* rsum) {
  int n = blockIdx.x, m = blockIdx.y, t = threadIdx.x;
  __shared__ float red[128];
  float v = (t < 100) ? tm[(n * 100 + m) * 100 + t] : -1e30f;
  red[t] = v; __syncthreads();
  for (int off = 64; off > 0; off >>= 1) { if (t < off) red[t] = fmaxf(red[t], red[t + off]); __syncthreads(); }
  float mx = red[0]; __syncthreads();
  float e = (t < 100) ? expf(v - mx) : 0.f;
  red[t] = e; __syncthreads();
  for (int off = 64; off > 0; off >>= 1) { if (t < off) red[t] += red[t + off]; __syncthreads(); }
  if (t == 0) { rmax[n * 100 + m] = mx; rsum[n * 100 + m] = red[0]; }
}

__global__ void tm_argmax_kernel(const float* tm, const float* cmax, const float* csum,
                                 const float* rmax, const float* rsum, int* tmidx) {
  int n = blockIdx.x, m = blockIdx.y, t = threadIdx.x;
  __shared__ float rv[128]; __shared__ int ri[128];
  float v = -1e30f;
  if (t < 100) {
    float x = tm[(n * 100 + m) * 100 + t];
    v = (expf(x - cmax[n * 100 + t]) / csum[n * 100 + t]) * (expf(x - rmax[n * 100 + m]) / rsum[n * 100 + m]);
  }
  rv[t] = v; ri[t] = t; __syncthreads();
  for (int off = 64; off > 0; off >>= 1) {
    if (t < off) {
      if (rv[t + off] > rv[t] || (rv[t + off] == rv[t] && ri[t + off] < ri[t])) { rv[t] = rv[t + off]; ri[t] = ri[t + off]; }
    }
    __syncthreads();
  }
  if (t == 0) tmidx[n * 100 + m] = ri[0];
}

__global__ void topicp_kernel(const float* t0raw, const float* t1raw, const int* tmidx, float* topicp) {
  int n = blockIdx.x, m = blockIdx.y, j = threadIdx.x;
  if (j >= 96) return;
  int g = tmidx[300 + m];
  float a, b;
  if (j < 48) {
    a = t0raw[(n * 96 + 2 * j) * 100 + m];
    b = t0raw[(n * 96 + 2 * j + 1) * 100 + m];
  } else {
    int d0 = 2 * j - 96;
    a = t1raw[(n * 96 + d0) * 100 + g];
    b = t1raw[(n * 96 + d0 + 1) * 100 + g];
  }
  topicp[(n * 100 + m) * 96 + j] = 0.5f * (a + b);
}

__global__ void seedsF_kernel(const float* seeds, const float* topicp, float* seedsF) {
  int n = blockIdx.x, k = blockIdx.y, t = threadIdx.x;
  float v;
  if (t < 160) {
    int s = (t * 256) / 160;
    int e = ((t + 1) * 256 + 159) / 160;
    float a = 0.f;
    for (int i = s; i < e; i++) a += seeds[(n * 100 + k) * 256 + i];
    v = a / (float)(e - s);
  } else {
    v = topicp[(n * 100 + k) * 96 + (t - 160)];
  }
  float2 r = blk_sum2_256(v, v * v);
  float mu = r.x * (1.f / 256.f);
  float var = r.y * (1.f / 256.f) - mu * mu;
  seedsF[(n * 100 + k) * 256 + t] = (v - mu) * rsqrtf(var + 1e-5f);
}

__global__ void transpose_seeds_kernel(const float* sF, float* sT) {
  long i = (long)blockIdx.x * 256 + threadIdx.x;
  if (i >= 4L * 25600) return;
  int n = (int)(i / 25600); int r = (int)(i % 25600); int k = r / 256; int d = r % 256;
  sT[n * 25600 + d * 100 + k] = sF[i];
}

// ---------------- dmatrix post-processing ----------------
__global__ void softmax_rows_kernel(const float* dm, float* prob) {
  long row = blockIdx.x; int t = threadIdx.x;
  __shared__ float red[128];
  float v = (t < 100) ? dm[row * 100 + t] : -1e30f;
  red[t] = v; __syncthreads();
  for (int off = 64; off > 0; off >>= 1) { if (t < off) red[t] = fmaxf(red[t], red[t + off]); __syncthreads(); }
  float mx = red[0]; __syncthreads();
  float e = (t < 100) ? expf(v - mx) : 0.f;
  red[t] = e; __syncthreads();
  for (int off = 64; off > 0; off >>= 1) { if (t < off) red[t] += red[t + off]; __syncthreads(); }
  float s = red[0];
  if (t < 100) prob[row * 100 + t] = e / s;
}

__global__ void colsum_kernel(const float* prob, float* cs0, float* cs1) {
  int k = blockIdx.x, n = blockIdx.y, half = blockIdx.z;
  int t = threadIdx.x;
  const float* p = prob + ((long)n * 8192 + half * 4096) * 100 + k;
  float s = 0.f;
  for (int m = t; m < 4096; m += 256) s += p[(long)m * 100];
  float2 r = blk_sum2_256(s, 0.f);
  if (t == 0) (half ? cs1 : cs0)[n * 100 + k] = r.x;
}

__global__ void topk_kernel(const float* cs0, const float* cs1, int* inds) {
  int n = blockIdx.x, t = threadIdx.x;
  __shared__ float rv[128]; __shared__ int ri[128]; __shared__ int sbest;
  float base = (t < 100) ? cs0[n * 100 + t] * cs1[n * 100 + t] : -1.f;
  for (int kk = 0; kk < 6; kk++) {
    rv[t] = base; ri[t] = t; __syncthreads();
    for (int off = 64; off > 0; off >>= 1) {
      if (t < off) {
        if (rv[t + off] > rv[t] || (rv[t + off] == rv[t] && ri[t + off] < ri[t])) { rv[t] = rv[t + off]; ri[t] = ri[t + off]; }
      }
      __syncthreads();
    }
    if (t == 0) { inds[n * 6 + kk] = ri[0]; sbest = ri[0]; }
    __syncthreads();
    if (t == sbest) base = -1.f;
    __syncthreads();
  }
}

__global__ void argmax_rows_kernel(const float* dm, int* amax) {
  int row = blockIdx.x * 256 + threadIdx.x;
  if (row >= 32768) return;
  const float* p = dm + (long)row * 100;
  float best = p[0]; int bi = 0;
  for (int k = 1; k < 100; k++) { float v = p[k]; if (v > best) { best = v; bi = k; } }
  amax[row] = bi;
}

// ---------------- sample loop ----------------
__global__ __launch_bounds__(1024) void build_ord_kernel(
    const int* amax, const int* inds, int kk, int* ord0, int* ord1, int* cnt0, int* cnt1)
{
  int n = blockIdx.x, half = blockIdx.y;
  int t = threadIdx.x;
  __shared__ int ts[1024];
  int target = inds[n * 6 + kk];
  const int* am = amax + n * 8192 + half * 4096;
  int f[4]; int lc = 0;
  #pragma unroll
  for (int j = 0; j < 4; j++) { f[j] = (am[t * 4 + j] == target) ? 1 : 0; lc += f[j]; }
  ts[t] = lc; __syncthreads();
  for (int off = 1; off < 1024; off <<= 1) {
    int add = (t >= off) ? ts[t - off] : 0;
    __syncthreads();
    ts[t] += add;
    __syncthreads();
  }
  int total = ts[1023];
  int run = (t == 0) ? 0 : ts[t - 1];
  int* ord = (half ? ord1 : ord0) + n * 4096;
  #pragma unroll
  for (int j = 0; j < 4; j++) {
    int i = t * 4 + j;
    if (f[j]) { ord[run] = i; run++; }
    else { ord[total + (i - run)] = i; }
  }
  if (t == 0) (half ? cnt1 : cnt0)[n] = total;
}

__global__ void cond_kernel(const int* c0, const int* c1, float* condf) {
  int a = c0[0] + c0[1] + c0[2] + c0[3];
  int b = c1[0] + c1[1] + c1[2] + c1[3];
  condf[0] = (a > 0 && b > 0) ? 1.f : 0.f;
}

__global__ void gather_kernel(float* nf, const float* fcur, const int* ord, const int* cnt) {
  int n = blockIdx.y;
  long i = (long)blockIdx.x * 256 + threadIdx.x;
  int r = (int)(i >> 8), c = (int)(i & 255);
  float v = 0.f;
  if (r < cnt[n]) v = fcur[((long)n * 4096 + ord[n * 4096 + r]) * 256 + c];
  nf[(long)n * 1048576 + i] = v;
}

__global__ void scatter_kernel(float* up, const float* nf, const int* ord, const int* cnt, const float* condf) {
  int n = blockIdx.y;
  long i = (long)blockIdx.x * 256 + threadIdx.x;
  int r = (int)(i >> 8), c = (int)(i & 255);
  if (r < cnt[n]) {
    up[((long)n * 4096 + ord[n * 4096 + r]) * 256 + c] += nf[(long)n * 1048576 + i] * condf[0];
  }
}

__global__ void final_mix_kernel(const float* fcur, const float* up, const int* amax,
                                 const int* inds, float* out, int half) {
  int n = blockIdx.y;
  long i = (long)blockIdx.x * 256 + threadIdx.x;
  int l = (int)(i >> 8);
  int a = amax[n * 8192 + half * 4096 + l];
  const int* in_ = inds + n * 6;
  bool member = (a == in_[0]) | (a == in_[1]) | (a == in_[2]) | (a == in_[3]) | (a == in_[4]) | (a == in_[5]);
  long idx = (long)n * 1048576 + i;
  float res = (member ? 0.f : 1.f) * fcur[idx] + up[idx];
  out[(long)half * 4194304 + idx] = res;
}

__global__ void tmi_kernel(const float* dmat, float* out) {
  int n = blockIdx.y, half = blockIdx.z;
  long i = (long)blockIdx.x * 256 + threadIdx.x;  // < 409600
  const float* dm = dmat + (long)n * 819200 + (long)half * 409600;
  int a = (int)(i / 100), b = (int)(i % 100);
  int y = a >> 6, x = a & 63;
  float sum = 0.f;
  for (int dy = -1; dy <= 1; dy++) {
    int yy = y + dy; if (yy < 0 || yy >= 64) continue;
    for (int dx = -1; dx <= 1; dx++) {
      int xc = x + dx; if (xc < 0 || xc >= 64) continue;
      sum += dm[b * 4096 + yy * 64 + xc];
    }
  }
  float val = dm[i] * (sum * (1.f / 9.f));
  out[8388608L + (long)half * 1638400 + (long)n * 409600 + i] = val;
}

// ---------------------------------------------------------------------------
struct Seg { const float* p; int rows; long bstride; };

extern "C" void kernel_launch(void* const* d_in, const int* in_sizes, int n_in,
                              void* d_out, int out_size, void* d_ws, size_t ws_size,
                              hipStream_t stream)
{
  (void)in_sizes; (void)n_in; (void)out_size; (void)ws_size;
  const float* feat0_in = (const float*)d_in[0];
  const float* feat1_in = (const float*)d_in[1];
  const float* topic0 = (const float*)d_in[2];
  const float* topic1 = (const float*)d_in[3];
  const float* seed_tokens = (const float*)d_in[4];
  const float* Wq = (const float*)d_in[5];
  const float* Wk = (const float*)d_in[6];
  const float* Wv = (const float*)d_in[7];
  const float* Wm = (const float*)d_in[8];
  const float* W1 = (const float*)d_in[9];
  const float* W2 = (const float*)d_in[10];
  float* out = (float*)d_out;

  float* base = (float*)d_ws;
  long off = 0;
  auto alloc = [&](long n) -> float* { float* p = base + off; off += (n + 255) & ~255L; return p; };
  float* f0    = alloc(4194304);
  float* f1    = alloc(4194304);
  float* qb    = alloc(4194304);   // Q / h2
  float* kb    = alloc(8388608);   // K / msg / cat / prob
  float* vb    = alloc(8388608);   // V / msg2 / h1
  float* seeds = alloc(102400);
  float* kvks  = alloc(33792);     // KV (32768) + Ksum (1024)
  float* dmat  = alloc(3276800);
  float* nf0   = alloc(4194304);
  float* nf1   = alloc(4194304);
  float* up0   = alloc(4194304);
  float* up1   = alloc(4194304);
  float* tmb   = alloc(40000);
  float* cmaxb = alloc(400); float* csumb = alloc(400);
  float* rmaxb = alloc(400); float* rsumb = alloc(400);
  float* topicp= alloc(38400);
  float* sF    = alloc(102400);
  float* sT    = alloc(102400);
  float* cs0   = alloc(400);
  float* cs1   = alloc(400);
  float* condf = alloc(256);
  int* tmidx = (int*)alloc(400);
  int* amax  = (int*)alloc(32768);
  int* inds  = (int*)alloc(256);
  int* cnt0  = (int*)alloc(256);
  int* cnt1  = (int*)alloc(256);
  int* ord0  = (int*)alloc(16384);
  int* ord1  = (int*)alloc(16384);

  // enc layer: x (fp32, in-place), source = up to 2 segments.
  // Activations (elu+1 for Q/K, row-mask for V) fused into GEMM epilogue.
  auto enc = [&](float* x, int l, Seg s0, Seg s1, int layer, const int* xc, const int* sc) {
    int s_len = s0.rows + s1.rows;
    const float* wq = Wq + (long)layer * 65536;
    const float* wk = Wk + (long)layer * 65536;
    const float* wv = Wv + (long)layer * 65536;
    const float* wm = Wm + (long)layer * 65536;
    const float* w1 = W1 + (long)layer * 262144;
    const float* w2 = W2 + (long)layer * 131072;
    // Q = elu(x@Wq)+1 (rows >= xc zeroed) -> qb
    launch_gemm(stream, x, wq, qb, l, 256, 256, (long)l * 256, 0, (long)l * 256, xc, 2, 1.f);
    // K = elu(src@Wk)+1, V = src@Wv (rows >= sc zeroed)
    long roff = 0;
    Seg ss[2] = { s0, s1 };
    for (int i = 0; i < 2; i++) {
      if (ss[i].rows <= 0) continue;
      launch_gemm(stream, ss[i].p, wk, kb + roff * 256, ss[i].rows, 256, 256, ss[i].bstride, 0, (long)s_len * 256, sc, 2, 1.f);
      launch_gemm(stream, ss[i].p, wv, vb + roff * 256, ss[i].rows, 256, 256, ss[i].bstride, 0, (long)s_len * 256, sc, 0, 1.f);
      roff += ss[i].rows;
    }
    // KV, Ksum
    hipMemsetAsync(kvks, 0, 33792 * sizeof(float), stream);
    int nch = (s_len + 1023) / 1024;
    kv_kernel<<<dim3(4, 8, nch), dim3(32, 32), 0, stream>>>(kb, vb, kvks, kvks + 32768, s_len, 1.f / (float)s_len, sc, 1024);
    // msg (fused Z) -> kb (K dead)
    zmsg_kernel<<<dim3(4, (l + 7) / 8), 256, 0, stream>>>(qb, kvks, kvks + 32768, kb, l, (float)s_len);
    // msg2 = msg @ Wm -> vb (V dead)
    launch_gemm(stream, kb, wm, vb, l, 256, 256, (long)l * 256, 0, (long)l * 256, xc, 0, 1.f);
    // cat = [x, LN(msg2)] -> kb
    ln_cat_kernel<<<4 * l, 256, 0, stream>>>(kb, x, vb);
    // h1 = relu(cat @ W1) -> vb
    launch_gemm(stream, kb, w1, vb, l, 512, 512, (long)l * 512, 0, (long)l * 512, xc, 1, 1.f);
    // h2 = h1 @ W2 -> qb
    launch_gemm(stream, vb, w2, qb, l, 256, 512, (long)l * 512, 0, (long)l * 256, xc, 0, 1.f);
    // x += LN(h2)
    add_ln_kernel<<<4 * l, 256, 0, stream>>>(x, qb);
  };

  // ---- init ----
  cvt_kernel<<<16384, 256, 0, stream>>>(f0, feat0_in, 4194304);
  cvt_kernel<<<16384, 256, 0, stream>>>(f1, feat1_in, 4194304);
  bcast_seeds_kernel<<<400, 256, 0, stream>>>(seeds, seed_tokens);

  // ---- topic pipeline ----
  tm_build_kernel<<<dim3(4, 100), 128, 0, stream>>>(topic0, topic1, tmb);
  tm_colstats_kernel<<<dim3(4, 100), 128, 0, stream>>>(tmb, cmaxb, csumb);
  tm_rowstats_kernel<<<dim3(4, 100), 128, 0, stream>>>(tmb, rmaxb, rsumb);
  tm_argmax_kernel<<<dim3(4, 100), 128, 0, stream>>>(tmb, cmaxb, csumb, rmaxb, rsumb, tmidx);
  topicp_kernel<<<dim3(4, 100), 128, 0, stream>>>(topic0, topic1, tmidx, topicp);

  // ---- main encoder layers ----
  Seg segF0{ feat0_in, 4096, 1048576 };
  Seg segF1{ feat1_in, 4096, 1048576 };
  Seg segSeeds{ seeds, 100, 25600 };
  Seg segNone{ nullptr, 0, 0 };
  enc(seeds, 100, segF0, segF1, 0, nullptr, nullptr);
  enc(f0, 4096, segSeeds, segNone, 1, nullptr, nullptr);
  enc(f1, 4096, segSeeds, segNone, 1, nullptr, nullptr);
  enc(seeds, 100, segF0, segF1, 2, nullptr, nullptr);
  enc(f0, 4096, segSeeds, segNone, 3, nullptr, nullptr);
  enc(f1, 4096, segSeeds, segNone, 3, nullptr, nullptr);

  // ---- seeds final + dmatrix ----
  seedsF_kernel<<<dim3(4, 100), 256, 0, stream>>>(seeds, topicp, sF);
  transpose_seeds_kernel<<<400, 256, 0, stream>>>(sF, sT);
  launch_gemm(stream, feat0_in, sT, dmat, 4096, 100, 256, 1048576, 25600, 819200, nullptr, 0, 0.0625f);
  launch_gemm(stream, feat1_in, sT, dmat + 409600, 4096, 100, 256, 1048576, 25600, 819200, nullptr, 0, 0.0625f);

  float* prob = kb;
  softmax_rows_kernel<<<32768, 128, 0, stream>>>(dmat, prob);
  colsum_kernel<<<dim3(100, 4, 2), 256, 0, stream>>>(prob, cs0, cs1);
  topk_kernel<<<4, 128, 0, stream>>>(cs0, cs1, inds);
  argmax_rows_kernel<<<128, 256, 0, stream>>>(dmat, amax);

  hipMemsetAsync(up0, 0, 4194304 * sizeof(float), stream);
  hipMemsetAsync(up1, 0, 4194304 * sizeof(float), stream);

  // ---- sample loop ----
  for (int kk = 0; kk < 6; kk++) {
    build_ord_kernel<<<dim3(4, 2), 1024, 0, stream>>>(amax, inds, kk, ord0, ord1, cnt0, cnt1);
    cond_kernel<<<1, 1, 0, stream>>>(cnt0, cnt1, condf);
    gather_kernel<<<dim3(4096, 4), 256, 0, stream>>>(nf0, f0, ord0, cnt0);
    gather_kernel<<<dim3(4096, 4), 256, 0, stream>>>(nf1, f1, ord1, cnt1);
    Seg sN0{ nf0, 4096, 1048576 };
    Seg sN1{ nf1, 4096, 1048576 };
    for (int idt = 0; idt < 2; idt++) {
      int wA = 4 + idt * 2, wB = wA + 1;
      enc(nf0, 4096, sN0, segNone, wA, cnt0, cnt0);
      enc(nf1, 4096, sN1, segNone, wA, cnt1, cnt1);
      enc(nf0, 4096, sN1, segNone, wB, cnt0, cnt1);
      enc(nf1, 4096, sN0, segNone, wB, cnt1, cnt0);
    }
    scatter_kernel<<<dim3(4096, 4), 256, 0, stream>>>(up0, nf0, ord0, cnt0, condf);
    scatter_kernel<<<dim3(4096, 4), 256, 0, stream>>>(up1, nf1, ord1, cnt1, condf);
  }

  // ---- outputs ----
  final_mix_kernel<<<dim3(4096, 4), 256, 0, stream>>>(f0, up0, amax, inds, out, 0);
  final_mix_kernel<<<dim3(4096, 4), 256, 0, stream>>>(f1, up1, amax, inds, out, 1);
  tmi_kernel<<<dim3(1600, 4, 2), 256, 0, stream>>>(dmat, out);
}

// Round 5
// 8695.968 us; speedup vs baseline: 2.9200x; 2.7026x over previous
//
#include <hip/hip_runtime.h>
#include <math.h>

// N=4, L=S=4096, C=256, K=100, DT=96, NHEAD=8, D=32. FP32 I/O.
// Big GEMMs: bf16x3 split MFMA (hi*hi + hi*lo + lo*hi, fp32 acc) ~ fp32 fidelity.
// Weights pre-converted once per launch to transposed bf16 hi/lo planes.
// Workspace kept < 256 MiB (204 MB): msg2/h2 reuse qb; up01 aliases d_out.

typedef __attribute__((ext_vector_type(8))) short short8;
typedef __attribute__((ext_vector_type(4))) float f32x4;

__device__ __forceinline__ short f2bf(float f) {
  unsigned u = __float_as_uint(f);
  return (short)((u + 0x7FFFu + ((u >> 16) & 1u)) >> 16);
}
__device__ __forceinline__ float bf2f(short s) {
  return __uint_as_float(((unsigned)(unsigned short)s) << 16);
}

// ---------------------------------------------------------------------------
// Weight prep: per layer L, transposed [n][k] bf16 hi/lo planes.
// Layout (shorts, per layer stride 1310720):
//   +0       QKV group [768][256] hi, lo at +196608
//   +393216  Wm [256][256] hi, lo at +65536
//   +524288  W1 [512][512] hi, lo at +262144
//   +1048576 W2 [256][512] hi, lo at +131072
// ---------------------------------------------------------------------------
__global__ void prep_w_kernel(const float* __restrict__ Wq, const float* __restrict__ Wk,
                              const float* __restrict__ Wv, const float* __restrict__ Wm,
                              const float* __restrict__ W1, const float* __restrict__ W2,
                              short* __restrict__ wb) {
  long i = (long)blockIdx.x * 256 + threadIdx.x;
  if (i >= 8L * 655360) return;
  int L = (int)(i / 655360);
  int r = (int)(i % 655360);
  long base = (long)L * 1310720;
  float v; long dhi; int loD;
  if (r < 196608) {
    int n = r >> 8, k = r & 255;
    const float* s = (n < 256) ? (Wq + (long)L * 65536)
                   : (n < 512) ? (Wk + (long)L * 65536) : (Wv + (long)L * 65536);
    v = s[k * 256 + (n & 255)];
    dhi = base + (long)n * 256 + k; loD = 196608;
  } else if (r < 262144) {
    int j = r - 196608; int n = j >> 8, k = j & 255;
    v = Wm[(long)L * 65536 + k * 256 + n];
    dhi = base + 393216 + (long)n * 256 + k; loD = 65536;
  } else if (r < 524288) {
    int j = r - 262144; int n = j >> 9, k = j & 511;
    v = W1[(long)L * 262144 + (long)k * 512 + n];
    dhi = base + 524288 + (long)n * 512 + k; loD = 262144;
  } else {
    int j = r - 524288; int n = j >> 9, k = j & 511;
    v = W2[(long)L * 131072 + (long)k * 256 + n];
    dhi = base + 1048576 + (long)n * 512 + k; loD = 131072;
  }
  short h = f2bf(v);
  wb[dhi] = h;
  wb[dhi + loD] = f2bf(v - bf2f(h));
}

// ---------------------------------------------------------------------------
// Prepped-B batched GEMM. A fp32 (optional dual-source LN for h1), B = prepped
// bf16 hi/lo [Ntot][Kd]. Up to 3 outputs routed by column block (each outW
// wide). Batch map: ab = (b & bmask) ^ bxor (A and rowcount). Rows >= cnt[ab]
// are neither computed nor written (consumers mask by cnt).
// modes: 0 none, 1 relu, 2 elu(x)+1.
// ---------------------------------------------------------------------------
__global__ __launch_bounds__(256) void gemm_pb_kernel(
    const float* __restrict__ A, const float* __restrict__ A2,
    const float* __restrict__ mu, const float* __restrict__ rsig,
    const short* __restrict__ Bh, int loDelta,
    float* __restrict__ C0, float* __restrict__ C1, float* __restrict__ C2,
    int M, int Kd, int outW, long sA, long sC,
    const int* __restrict__ cnt, int bmask, int bxor,
    int mode0, int mode1, int mode2, float alpha)
{
  int b = blockIdx.z;
  int ab = (b & bmask) ^ bxor;
  int cntb = cnt ? cnt[ab] : M;
  int row0 = blockIdx.y * 128;
  if (row0 >= cntb) return;
  const float* Ab = A + (long)ab * sA;
  const float* A2b = A2 ? A2 + (long)ab * sA : nullptr;
  const float* mub = mu ? mu + (long)ab * M : nullptr;
  const float* rsb = rsig ? rsig + (long)ab * M : nullptr;
  int colg = blockIdx.x * 128;
  int sel = colg / outW;
  float* Cb = (sel == 0 ? C0 : (sel == 1 ? C1 : C2)) + (long)b * sC;
  int mode = (sel == 0 ? mode0 : (sel == 1 ? mode1 : mode2));
  int colo = colg % outW;
  int aStride = A2b ? 256 : Kd;

  int t = threadIdx.x;
  int lane = t & 63, wid = t >> 6, wm = wid >> 1, wn = wid & 1;
  int fi = lane & 15, fq = lane >> 4;

  __shared__ __align__(16) short Ah[128][40];
  __shared__ __align__(16) short Al[128][40];
  __shared__ __align__(16) short Bsh[128][40];
  __shared__ __align__(16) short Bsl[128][40];

  f32x4 acc[4][4];
  #pragma unroll
  for (int i = 0; i < 4; i++)
    #pragma unroll
    for (int j = 0; j < 4; j++)
      acc[i][j] = (f32x4){0.f, 0.f, 0.f, 0.f};

  int tr = t >> 3, tc = (t & 7) * 4;
  int nc = t >> 1, kh = (t & 1) * 16;

  for (int k0 = 0; k0 < Kd; k0 += 32) {
    bool useA2 = (A2b != nullptr) && (k0 >= 256);
    const float* Asrc = useA2 ? A2b : Ab;
    int kcol = useA2 ? (k0 - 256) : k0;
    #pragma unroll
    for (int p = 0; p < 4; p++) {
      int r = tr + p * 32, gr = row0 + r;
      float4 v = make_float4(0.f, 0.f, 0.f, 0.f);
      if (gr < M) {
        v = *(const float4*)&Asrc[(long)gr * aStride + kcol + tc];
        if (useA2) {
          float m = mub[gr], s = rsb[gr];
          v.x = (v.x - m) * s; v.y = (v.y - m) * s; v.z = (v.z - m) * s; v.w = (v.w - m) * s;
        }
      }
      float vv[4] = {v.x, v.y, v.z, v.w};
      #pragma unroll
      for (int e = 0; e < 4; e++) {
        short h = f2bf(vv[e]);
        Ah[r][tc + e] = h;
        Al[r][tc + e] = f2bf(vv[e] - bf2f(h));
      }
    }
    {
      const short* bs = Bh + (long)(colg + nc) * Kd + k0 + kh;
      *(short8*)&Bsh[nc][kh]     = *(const short8*)bs;
      *(short8*)&Bsh[nc][kh + 8] = *(const short8*)(bs + 8);
      *(short8*)&Bsl[nc][kh]     = *(const short8*)(bs + loDelta);
      *(short8*)&Bsl[nc][kh + 8] = *(const short8*)(bs + loDelta + 8);
    }
    __syncthreads();
    short8 ah[4], al[4], bh[4], bl[4];
    #pragma unroll
    for (int i = 0; i < 4; i++) {
      ah[i] = *(const short8*)&Ah[wm * 64 + i * 16 + fi][fq * 8];
      al[i] = *(const short8*)&Al[wm * 64 + i * 16 + fi][fq * 8];
    }
    #pragma unroll
    for (int j = 0; j < 4; j++) {
      bh[j] = *(const short8*)&Bsh[wn * 64 + j * 16 + fi][fq * 8];
      bl[j] = *(const short8*)&Bsl[wn * 64 + j * 16 + fi][fq * 8];
    }
    #pragma unroll
    for (int i = 0; i < 4; i++)
      #pragma unroll
      for (int j = 0; j < 4; j++) {
        acc[i][j] = __builtin_amdgcn_mfma_f32_16x16x32_bf16(ah[i], bh[j], acc[i][j], 0, 0, 0);
        acc[i][j] = __builtin_amdgcn_mfma_f32_16x16x32_bf16(ah[i], bl[j], acc[i][j], 0, 0, 0);
        acc[i][j] = __builtin_amdgcn_mfma_f32_16x16x32_bf16(al[i], bh[j], acc[i][j], 0, 0, 0);
      }
    __syncthreads();
  }
  #pragma unroll
  for (int i = 0; i < 4; i++) {
    #pragma unroll
    for (int reg = 0; reg < 4; reg++) {
      int gr = row0 + wm * 64 + i * 16 + fq * 4 + reg;
      if (gr >= M || gr >= cntb) continue;
      #pragma unroll
      for (int j = 0; j < 4; j++) {
        int cc = colo + wn * 64 + j * 16 + fi;
        float v = acc[i][j][reg] * alpha;
        if (mode == 1) { if (v < 0.f) v = 0.f; }
        else if (mode == 2) { v = (v > 0.f) ? (v + 1.f) : expf(v); }
        Cb[(long)gr * outW + cc] = v;
      }
    }
  }
}

// ---------------------------------------------------------------------------
// fp32-B MFMA GEMM (dmatrix only; N=100 needs bounds).
// ---------------------------------------------------------------------------
__global__ __launch_bounds__(256) void gemm_f32b_kernel(
    const float* __restrict__ A, const float* __restrict__ B, float* __restrict__ C,
    int M, int N, int Kd, long sA, long sB, long sC, float alpha)
{
  int b = blockIdx.z;
  const float* Ab = A + (long)b * sA;
  const float* Bb = B + (long)b * sB;
  float* Cb = C + (long)b * sC;
  int row0 = blockIdx.y * 128, col0 = blockIdx.x * 128;
  int t = threadIdx.x;
  int lane = t & 63, wid = t >> 6, wm = wid >> 1, wn = wid & 1;
  int fi = lane & 15, fq = lane >> 4;
  __shared__ __align__(16) short Ah[128][40];
  __shared__ __align__(16) short Al[128][40];
  __shared__ __align__(16) short Bsh[128][40];
  __shared__ __align__(16) short Bsl[128][40];
  f32x4 acc[4][4];
  #pragma unroll
  for (int i = 0; i < 4; i++)
    #pragma unroll
    for (int j = 0; j < 4; j++)
      acc[i][j] = (f32x4){0.f, 0.f, 0.f, 0.f};
  int tr = t >> 3, tc = (t & 7) * 4;
  int bn = (t & 31) * 4, bk = t >> 5;
  for (int k0 = 0; k0 < Kd; k0 += 32) {
    #pragma unroll
    for (int p = 0; p < 4; p++) {
      int r = tr + p * 32, gr = row0 + r;
      float4 v = make_float4(0.f, 0.f, 0.f, 0.f);
      if (gr < M) v = *(const float4*)&Ab[(long)gr * Kd + k0 + tc];
      float vv[4] = {v.x, v.y, v.z, v.w};
      #pragma unroll
      for (int e = 0; e < 4; e++) {
        short h = f2bf(vv[e]); Ah[r][tc + e] = h; Al[r][tc + e] = f2bf(vv[e] - bf2f(h));
      }
    }
    #pragma unroll
    for (int p = 0; p < 4; p++) {
      int kk = bk + p * 8;
      long gkN = (long)(k0 + kk) * N;
      #pragma unroll
      for (int e = 0; e < 4; e++) {
        int gc = col0 + bn + e;
        float v = (gc < N) ? Bb[gkN + gc] : 0.f;
        short h = f2bf(v); Bsh[bn + e][kk] = h; Bsl[bn + e][kk] = f2bf(v - bf2f(h));
      }
    }
    __syncthreads();
    short8 ah[4], al[4], bh[4], bl[4];
    #pragma unroll
    for (int i = 0; i < 4; i++) {
      ah[i] = *(const short8*)&Ah[wm * 64 + i * 16 + fi][fq * 8];
      al[i] = *(const short8*)&Al[wm * 64 + i * 16 + fi][fq * 8];
    }
    #pragma unroll
    for (int j = 0; j < 4; j++) {
      bh[j] = *(const short8*)&Bsh[wn * 64 + j * 16 + fi][fq * 8];
      bl[j] = *(const short8*)&Bsl[wn * 64 + j * 16 + fi][fq * 8];
    }
    #pragma unroll
    for (int i = 0; i < 4; i++)
      #pragma unroll
      for (int j = 0; j < 4; j++) {
        acc[i][j] = __builtin_amdgcn_mfma_f32_16x16x32_bf16(ah[i], bh[j], acc[i][j], 0, 0, 0);
        acc[i][j] = __builtin_amdgcn_mfma_f32_16x16x32_bf16(ah[i], bl[j], acc[i][j], 0, 0, 0);
        acc[i][j] = __builtin_amdgcn_mfma_f32_16x16x32_bf16(al[i], bh[j], acc[i][j], 0, 0, 0);
      }
    __syncthreads();
  }
  #pragma unroll
  for (int i = 0; i < 4; i++) {
    #pragma unroll
    for (int reg = 0; reg < 4; reg++) {
      int gr = row0 + wm * 64 + i * 16 + fq * 4 + reg;
      if (gr >= M) continue;
      #pragma unroll
      for (int j = 0; j < 4; j++) {
        int gc = col0 + wn * 64 + j * 16 + fi;
        if (gc < N) Cb[(long)gr * N + gc] = acc[i][j][reg] * alpha;
      }
    }
  }
}

// ---------------------------------------------------------------------------
__device__ __forceinline__ float2 blk_sum2_256(float a, float b)
{
  __shared__ float sa[4], sb[4];
  int lane = threadIdx.x & 63, w = threadIdx.x >> 6;
  #pragma unroll
  for (int off = 32; off > 0; off >>= 1) { a += __shfl_down(a, off, 64); b += __shfl_down(b, off, 64); }
  if (lane == 0) { sa[w] = a; sb[w] = b; }
  __syncthreads();
  float ra = sa[0] + sa[1] + sa[2] + sa[3];
  float rb = sb[0] + sb[1] + sb[2] + sb[3];
  __syncthreads();
  return make_float2(ra, rb);
}

__global__ void cvt_kernel(float* dst, const float* src, long n) {
  long i = (long)blockIdx.x * 256 + threadIdx.x;
  if (i < n) dst[i] = src[i];
}

__global__ void bcast_seeds_kernel(float* seeds, const float* st) {
  long i = (long)blockIdx.x * 256 + threadIdx.x;
  if (i < 4L * 25600) seeds[i] = st[i % 25600];
}

// KV[n,h,d,e] += sum_s K*V/s ; Ksum[n,h,d] += sum_s K  (valid source rows only)
__global__ __launch_bounds__(1024) void kv_kernel(
    const float* __restrict__ Kb, const float* __restrict__ Vb,
    float* __restrict__ KV, float* __restrict__ Ksum,
    int s_len, float inv_s, const int* __restrict__ cnt, int bmask, int cx, int chunk)
{
  int n = blockIdx.x, h = blockIdx.y;
  int slim = cnt ? min(cnt[(n & bmask) ^ cx], s_len) : s_len;
  int s0b = blockIdx.z * chunk;
  int send = min(s0b + chunk, slim);
  if (s0b >= send) return;
  __shared__ float Kt[32][33];
  __shared__ float Vt[32][33];
  int tx = threadIdx.x, ty = threadIdx.y;
  float acc = 0.f, ks = 0.f;
  for (int s0 = s0b; s0 < send; s0 += 32) {
    int sr = s0 + ty;
    float kvv = 0.f, vvv = 0.f;
    if (sr < send) {
      long base = ((long)n * s_len + sr) * 256 + h * 32 + tx;
      kvv = Kb[base]; vvv = Vb[base];
    }
    Kt[ty][tx] = kvv; Vt[ty][tx] = vvv;
    __syncthreads();
    #pragma unroll
    for (int j = 0; j < 32; j++) acc += Kt[j][ty] * Vt[j][tx];
    if (tx == 0) {
      #pragma unroll
      for (int j = 0; j < 32; j++) ks += Kt[j][ty];
    }
    __syncthreads();
  }
  atomicAdd(&KV[((n * 8 + h) * 32 + ty) * 32 + tx], acc * inv_s);
  if (tx == 0) atomicAdd(&Ksum[(n * 8 + h) * 32 + ty], ks);
}

// msg = (Q·KV) * Z * s ; Z = 1/(Q·Ksum + 1e-6); rows < cnt only
__global__ __launch_bounds__(256) void zmsg_kernel(
    const float* __restrict__ Q, const float* __restrict__ KV,
    const float* __restrict__ Ksum, float* __restrict__ msg, int l, float s_len,
    const int* __restrict__ cnt)
{
  int n = blockIdx.x;
  int cb = cnt ? min(cnt[n], l) : l;
  int r0 = blockIdx.y * 8;
  if (r0 >= cb) return;
  int t = threadIdx.x;
  __shared__ float KVs[8192];
  __shared__ float QL[256];
  __shared__ float Zl[8];
  for (int i = t; i < 8192; i += 256) KVs[i] = KV[n * 8192 + i];
  float Ks = Ksum[n * 256 + t];
  __syncthreads();
  int h = t >> 5, e = t & 31;
  for (int rr = 0; rr < 8; rr++) {
    int row = r0 + rr;
    if (row >= cb) break;
    long base = ((long)n * l + row) * 256;
    QL[t] = Q[base + t];
    __syncthreads();
    float p = QL[t] * Ks;
    #pragma unroll
    for (int off = 16; off > 0; off >>= 1) p += __shfl_down(p, off, 32);
    if (e == 0) Zl[h] = 1.f / (p + 1e-6f);
    __syncthreads();
    float acc = 0.f;
    const float* kvh = KVs + h * 1024;
    #pragma unroll
    for (int d = 0; d < 32; d++) acc += QL[h * 32 + d] * kvh[d * 32 + e];
    msg[base + t] = acc * Zl[h] * s_len;
    __syncthreads();
  }
}

// per-row LN stats of m2 (rows < cnt)
__global__ void ln_stats_kernel(const float* __restrict__ m2, float* __restrict__ mu,
                                float* __restrict__ rsig, int l, const int* __restrict__ cnt) {
  long row = blockIdx.x; int t = threadIdx.x;
  int b = (int)(row / l), r = (int)(row % l);
  if (cnt && r >= cnt[b]) return;
  float v = m2[row * 256 + t];
  float2 s = blk_sum2_256(v, v * v);
  if (t == 0) {
    float m = s.x * (1.f / 256.f);
    float var = s.y * (1.f / 256.f) - m * m;
    mu[row] = m; rsig[row] = rsqrtf(var + 1e-5f);
  }
}

// x_row += LN(h2_row)  (rows < cnt)
__global__ void add_ln_kernel(float* __restrict__ x, const float* __restrict__ h2,
                              int l, const int* __restrict__ cnt) {
  long row = blockIdx.x; int t = threadIdx.x;
  int b = (int)(row / l), r = (int)(row % l);
  if (cnt && r >= cnt[b]) return;
  float v = h2[row * 256 + t];
  float2 s = blk_sum2_256(v, v * v);
  float m = s.x * (1.f / 256.f);
  float var = s.y * (1.f / 256.f) - m * m;
  x[row * 256 + t] += (v - m) * rsqrtf(var + 1e-5f);
}

// ---------------- topic pipeline ----------------
__global__ void tm_build_kernel(const float* t0, const float* t1, float* tm) {
  int n = blockIdx.x, m = blockIdx.y, l = threadIdx.x;
  if (l >= 100) return;
  float acc = 0.f;
  for (int d = 0; d < 96; d++)
    acc += t0[(n * 96 + d) * 100 + m] * t1[(n * 96 + d) * 100 + l];
  tm[(n * 100 + m) * 100 + l] = floorf(acc * 0.0625f);
}

__global__ void tm_colstats_kernel(const float* tm, float* cmax, float* csum) {
  int n = blockIdx.x, l = blockIdx.y, t = threadIdx.x;
  __shared__ float red[128];
  float v = (t < 100) ? tm[(n * 100 + t) * 100 + l] : -1e30f;
  red[t] = v; __syncthreads();
  for (int off = 64; off > 0; off >>= 1) { if (t < off) red[t] = fmaxf(red[t], red[t + off]); __syncthreads(); }
  float mx = red[0]; __syncthreads();
  float e = (t < 100) ? expf(v - mx) : 0.f;
  red[t] = e; __syncthreads();
  for (int off = 64; off > 0; off >>= 1) { if (t < off) red[t] += red[t + off]; __syncthreads(); }
  if (t == 0) { cmax[n * 100 + l] = mx; csum[n * 100 + l] = red[0]; }
}

__global__ void tm_rowstats_kernel(const float* tm, float* rmax, float* rsum) {
  int n = blockIdx.x, m = blockIdx.y, t = threadIdx.x;
  __shared__ float red[128];
  float v = (t < 100) ? tm[(n * 100 + m) * 100 + t] : -1e30f;
  red[t] = v; __syncthreads();
  for (int off = 64; off > 0; off >>= 1) { if (t < off) red[t] = fmaxf(red[t], red[t + off]); __syncthreads(); }
  float mx = red[0]; __syncthreads();
  float e = (t < 100) ? expf(v - mx) : 0.f;
  red[t] = e; __syncthreads();
  for (int off = 64; off > 0; off >>= 1) { if (t < off) red[t] += red[t + off]; __syncthreads(); }
  if (t == 0) { rmax[n * 100 + m] = mx; rsum[n * 100 + m] = red[0]; }
}

__global__ void tm_argmax_kernel(const float* tm, const float* cmax, const float* csum,
                                 const float* rmax, const float* rsum, int* tmidx) {
  int n = blockIdx.x, m = blockIdx.y, t = threadIdx.x;
  __shared__ float rv[128]; __shared__ int ri[128];
  float v = -1e30f;
  if (t < 100) {
    float x = tm[(n * 100 + m) * 100 + t];
    v = (expf(x - cmax[n * 100 + t]) / csum[n * 100 + t]) * (expf(x - rmax[n * 100 + m]) / rsum[n * 100 + m]);
  }
  rv[t] = v; ri[t] = t; __syncthreads();
  for (int off = 64; off > 0; off >>= 1) {
    if (t < off) {
      if (rv[t + off] > rv[t] || (rv[t + off] == rv[t] && ri[t + off] < ri[t])) { rv[t] = rv[t + off]; ri[t] = ri[t + off]; }
    }
    __syncthreads();
  }
  if (t == 0) tmidx[n * 100 + m] = ri[0];
}

__global__ void topicp_kernel(const float* t0raw, const float* t1raw, const int* tmidx, float* topicp) {
  int n = blockIdx.x, m = blockIdx.y, j = threadIdx.x;
  if (j >= 96) return;
  int g = tmidx[300 + m];
  float a, b;
  if (j < 48) {
    a = t0raw[(n * 96 + 2 * j) * 100 + m];
    b = t0raw[(n * 96 + 2 * j + 1) * 100 + m];
  } else {
    int d0 = 2 * j - 96;
    a = t1raw[(n * 96 + d0) * 100 + g];
    b = t1raw[(n * 96 + d0 + 1) * 100 + g];
  }
  topicp[(n * 100 + m) * 96 + j] = 0.5f * (a + b);
}

__global__ void seedsF_kernel(const float* seeds, const float* topicp, float* seedsF) {
  int n = blockIdx.x, k = blockIdx.y, t = threadIdx.x;
  float v;
  if (t < 160) {
    int s = (t * 256) / 160;
    int e = ((t + 1) * 256 + 159) / 160;
    float a = 0.f;
    for (int i = s; i < e; i++) a += seeds[(n * 100 + k) * 256 + i];
    v = a / (float)(e - s);
  } else {
    v = topicp[(n * 100 + k) * 96 + (t - 160)];
  }
  float2 r = blk_sum2_256(v, v * v);
  float m = r.x * (1.f / 256.f);
  float var = r.y * (1.f / 256.f) - m * m;
  seedsF[(n * 100 + k) * 256 + t] = (v - m) * rsqrtf(var + 1e-5f);
}

__global__ void transpose_seeds_kernel(const float* sF, float* sT) {
  long i = (long)blockIdx.x * 256 + threadIdx.x;
  if (i >= 4L * 25600) return;
  int n = (int)(i / 25600); int r = (int)(i % 25600); int k = r / 256; int d = r % 256;
  sT[n * 25600 + d * 100 + k] = sF[i];
}

// ---------------- dmatrix post ----------------
__global__ void softmax_rows_kernel(const float* dm, float* prob) {
  long row = blockIdx.x; int t = threadIdx.x;
  __shared__ float red[128];
  float v = (t < 100) ? dm[row * 100 + t] : -1e30f;
  red[t] = v; __syncthreads();
  for (int off = 64; off > 0; off >>= 1) { if (t < off) red[t] = fmaxf(red[t], red[t + off]); __syncthreads(); }
  float mx = red[0]; __syncthreads();
  float e = (t < 100) ? expf(v - mx) : 0.f;
  red[t] = e; __syncthreads();
  for (int off = 64; off > 0; off >>= 1) { if (t < off) red[t] += red[t + off]; __syncthreads(); }
  float s = red[0];
  if (t < 100) prob[row * 100 + t] = e / s;
}

__global__ void colsum_kernel(const float* prob, float* cs0, float* cs1) {
  int k = blockIdx.x, n = blockIdx.y, half = blockIdx.z;
  int t = threadIdx.x;
  const float* p = prob + ((long)n * 8192 + half * 4096) * 100 + k;
  float s = 0.f;
  for (int m = t; m < 4096; m += 256) s += p[(long)m * 100];
  float2 r = blk_sum2_256(s, 0.f);
  if (t == 0) (half ? cs1 : cs0)[n * 100 + k] = r.x;
}

__global__ void topk_kernel(const float* cs0, const float* cs1, int* inds) {
  int n = blockIdx.x, t = threadIdx.x;
  __shared__ float rv[128]; __shared__ int ri[128]; __shared__ int sbest;
  float base = (t < 100) ? cs0[n * 100 + t] * cs1[n * 100 + t] : -1.f;
  for (int kk = 0; kk < 6; kk++) {
    rv[t] = base; ri[t] = t; __syncthreads();
    for (int off = 64; off > 0; off >>= 1) {
      if (t < off) {
        if (rv[t + off] > rv[t] || (rv[t + off] == rv[t] && ri[t + off] < ri[t])) { rv[t] = rv[t + off]; ri[t] = ri[t + off]; }
      }
      __syncthreads();
    }
    if (t == 0) { inds[n * 6 + kk] = ri[0]; sbest = ri[0]; }
    __syncthreads();
    if (t == sbest) base = -1.f;
    __syncthreads();
  }
}

__global__ void argmax_rows_kernel(const float* dm, int* amax) {
  int row = blockIdx.x * 256 + threadIdx.x;
  if (row >= 32768) return;
  const float* p = dm + (long)row * 100;
  float best = p[0]; int bi = 0;
  for (int k = 1; k < 100; k++) { float v = p[k]; if (v > best) { best = v; bi = k; } }
  amax[row] = bi;
}

// ---------------- sample loop ----------------
__global__ __launch_bounds__(1024) void build_ord_kernel(
    const int* amax, const int* inds, int kk, int* ord8, int* cnt8)
{
  int n = blockIdx.x, half = blockIdx.y;
  int g = half * 4 + n;
  int t = threadIdx.x;
  __shared__ int ts[1024];
  int target = inds[n * 6 + kk];
  const int* am = amax + n * 8192 + half * 4096;
  int f[4]; int lc = 0;
  #pragma unroll
  for (int j = 0; j < 4; j++) { f[j] = (am[t * 4 + j] == target) ? 1 : 0; lc += f[j]; }
  ts[t] = lc; __syncthreads();
  for (int off = 1; off < 1024; off <<= 1) {
    int add = (t >= off) ? ts[t - off] : 0;
    __syncthreads();
    ts[t] += add;
    __syncthreads();
  }
  int total = ts[1023];
  int run = (t == 0) ? 0 : ts[t - 1];
  int* ord = ord8 + g * 4096;
  #pragma unroll
  for (int j = 0; j < 4; j++) {
    int i = t * 4 + j;
    if (f[j]) { ord[run] = i; run++; }
    else { ord[total + (i - run)] = i; }
  }
  if (t == 0) cnt8[g] = total;
}

__global__ void cond_kernel(const int* cnt8, float* condf) {
  int a = cnt8[0] + cnt8[1] + cnt8[2] + cnt8[3];
  int b = cnt8[4] + cnt8[5] + cnt8[6] + cnt8[7];
  condf[0] = (a > 0 && b > 0) ? 1.f : 0.f;
}

__global__ void gather_kernel(float* nf, const float* f01, const int* ord8, const int* cnt8) {
  int b = blockIdx.y, r = blockIdx.x;
  if (r >= cnt8[b]) return;
  int c = threadIdx.x;
  nf[((long)b * 4096 + r) * 256 + c] = f01[((long)b * 4096 + ord8[b * 4096 + r]) * 256 + c];
}

__global__ void scatter_kernel(float* up, const float* nf, const int* ord8,
                               const int* cnt8, const float* condf) {
  int b = blockIdx.y, r = blockIdx.x;
  if (r >= cnt8[b]) return;
  int c = threadIdx.x;
  up[((long)b * 4096 + ord8[b * 4096 + r]) * 256 + c] += nf[((long)b * 4096 + r) * 256 + c] * condf[0];
}

// out feat region and up alias the same memory: in-place read-modify-write,
// each thread touches exactly its own element.
__global__ void final_mix_kernel(const float* f01, float* out_up, const int* amax,
                                 const int* inds) {
  int b = blockIdx.y, half = b >> 2, n = b & 3;
  int l = blockIdx.x, c = threadIdx.x;
  int a = amax[n * 8192 + half * 4096 + l];
  const int* in_ = inds + n * 6;
  bool member = (a == in_[0]) | (a == in_[1]) | (a == in_[2]) | (a == in_[3]) | (a == in_[4]) | (a == in_[5]);
  long idx = ((long)b * 4096 + l) * 256 + c;
  float up = out_up[idx];
  out_up[idx] = (member ? 0.f : 1.f) * f01[idx] + up;
}

__global__ void tmi_kernel(const float* dmat, float* out) {
  int n = blockIdx.y, half = blockIdx.z;
  long i = (long)blockIdx.x * 256 + threadIdx.x;
  const float* dm = dmat + (long)n * 819200 + (long)half * 409600;
  int a = (int)(i / 100), b = (int)(i % 100);
  int y = a >> 6, x = a & 63;
  float sum = 0.f;
  for (int dy = -1; dy <= 1; dy++) {
    int yy = y + dy; if (yy < 0 || yy >= 64) continue;
    for (int dx = -1; dx <= 1; dx++) {
      int xc = x + dx; if (xc < 0 || xc >= 64) continue;
      sum += dm[b * 4096 + yy * 64 + xc];
    }
  }
  out[8388608L + (long)half * 1638400 + (long)n * 409600 + i] = dm[i] * (sum * (1.f / 9.f));
}

// ---------------------------------------------------------------------------
extern "C" void kernel_launch(void* const* d_in, const int* in_sizes, int n_in,
                              void* d_out, int out_size, void* d_ws, size_t ws_size,
                              hipStream_t stream)
{
  (void)in_sizes; (void)n_in; (void)out_size; (void)ws_size;
  const float* feat0_in = (const float*)d_in[0];
  const float* feat1_in = (const float*)d_in[1];
  const float* topic0 = (const float*)d_in[2];
  const float* topic1 = (const float*)d_in[3];
  const float* seed_tokens = (const float*)d_in[4];
  const float* Wq = (const float*)d_in[5];
  const float* Wk = (const float*)d_in[6];
  const float* Wv = (const float*)d_in[7];
  const float* Wm = (const float*)d_in[8];
  const float* W1 = (const float*)d_in[9];
  const float* W2 = (const float*)d_in[10];
  float* out = (float*)d_out;

  float* base = (float*)d_ws;
  long off = 0;
  auto alloc = [&](long n) -> float* { float* p = base + off; off += (n + 255) & ~255L; return p; };
  float* f01   = alloc(8388608);   // updated feat0|feat1 [8][4096][256]
  float* qb    = alloc(8388608);   // Q / msg2 / h2
  float* kb    = alloc(8388608);   // K / msg / h1 lower  (kb,vb contiguous)
  float* vb    = alloc(8388608);   // V / h1 upper
  float* nf    = alloc(8388608);
  float* mu    = alloc(32768);
  float* rsig  = alloc(32768);
  float* seeds = alloc(102400);
  float* kvks  = alloc(67840);     // KV [8][8192] + Ksum [8][256]
  float* dmat  = alloc(3276800);
  short* wbuf  = (short*)alloc(5242880);  // 10485760 shorts
  float* tmb   = alloc(40000);
  float* cmaxb = alloc(400); float* csumb = alloc(400);
  float* rmaxb = alloc(400); float* rsumb = alloc(400);
  float* topicp= alloc(38400);
  float* sF    = alloc(102400);
  float* sT    = alloc(102400);
  float* cs0   = alloc(400);
  float* cs1   = alloc(400);
  float* condf = alloc(256);
  int* tmidx = (int*)alloc(400);
  int* amax  = (int*)alloc(32768);
  int* inds  = (int*)alloc(256);
  int* cnt8  = (int*)alloc(256);
  int* ord8  = (int*)alloc(32768);
  float* up01 = out;               // aliases out's feat region (index-identical)

  auto WOFF = [](int l) -> long { return (long)l * 1310720; };

  auto gemm = [&](const float* A, const float* A2, long wOff, int loD,
                  float* c0, float* c1, float* c2,
                  int M, int Kd, int Ntot, int outW, long sA_, long sC_,
                  const int* cnt_, int bmask_, int bxor_,
                  int m0, int m1, int m2m, float al, int nb) {
    dim3 g(Ntot / 128, (M + 127) / 128, nb), blk(256);
    gemm_pb_kernel<<<g, blk, 0, stream>>>(A, A2, A2 ? mu : nullptr, A2 ? rsig : nullptr,
        wbuf + wOff, loD, c0, c1, c2, M, Kd, outW, sA_, sC_, cnt_, bmask_, bxor_, m0, m1, m2m, al);
  };

  // enc tail after Q/K/V in qb/kb/vb: kv -> zmsg(msg->kb) -> msg2->qb ->
  // stats -> h1->kb(+vb) -> h2->qb -> x += LN(h2)
  auto encTail = [&](float* x, int l, int s_len, int layer, int nb,
                     const int* cntX, const int* cntKV, int kvmask, int kvcx) {
    hipMemsetAsync(kvks, 0, 67840 * sizeof(float), stream);
    int nch = (s_len + 1023) / 1024;
    kv_kernel<<<dim3(nb, 8, nch), dim3(32, 32), 0, stream>>>(
        kb, vb, kvks, kvks + 65536, s_len, 1.f / (float)s_len, cntKV, kvmask, kvcx, 1024);
    zmsg_kernel<<<dim3(nb, (l + 7) / 8), 256, 0, stream>>>(
        qb, kvks, kvks + 65536, kb, l, (float)s_len, cntX);
    gemm(kb, nullptr, WOFF(layer) + 393216, 65536, qb, nullptr, nullptr,
         l, 256, 256, 256, (long)l * 256, (long)l * 256, cntX, 7, 0, 0, 0, 0, 1.f, nb);
    ln_stats_kernel<<<nb * l, 256, 0, stream>>>(qb, mu, rsig, l, cntX);
    gemm(x, qb, WOFF(layer) + 524288, 262144, kb, nullptr, nullptr,
         l, 512, 512, 512, (long)l * 256, (long)l * 512, cntX, 7, 0, 1, 0, 0, 1.f, nb);
    gemm(kb, nullptr, WOFF(layer) + 1048576, 131072, qb, nullptr, nullptr,
         l, 512, 256, 256, (long)l * 512, (long)l * 256, cntX, 7, 0, 0, 0, 0, 1.f, nb);
    add_ln_kernel<<<nb * l, 256, 0, stream>>>(x, qb, l, cntX);
  };

  // ---- init ----
  cvt_kernel<<<16384, 256, 0, stream>>>(f01, feat0_in, 4194304);
  cvt_kernel<<<16384, 256, 0, stream>>>(f01 + 4194304, feat1_in, 4194304);
  bcast_seeds_kernel<<<400, 256, 0, stream>>>(seeds, seed_tokens);
  prep_w_kernel<<<20480, 256, 0, stream>>>(Wq, Wk, Wv, Wm, W1, W2, wbuf);

  // ---- topic pipeline ----
  tm_build_kernel<<<dim3(4, 100), 128, 0, stream>>>(topic0, topic1, tmb);
  tm_colstats_kernel<<<dim3(4, 100), 128, 0, stream>>>(tmb, cmaxb, csumb);
  tm_rowstats_kernel<<<dim3(4, 100), 128, 0, stream>>>(tmb, rmaxb, rsumb);
  tm_argmax_kernel<<<dim3(4, 100), 128, 0, stream>>>(tmb, cmaxb, csumb, rmaxb, rsumb, tmidx);
  topicp_kernel<<<dim3(4, 100), 128, 0, stream>>>(topic0, topic1, tmidx, topicp);

  // ---- main encoder layers ----
  auto encSeedLayer = [&](int layer) {
    gemm(seeds, nullptr, WOFF(layer), 196608, qb, nullptr, nullptr,
         100, 256, 256, 256, 25600, 25600, nullptr, 7, 0, 2, 0, 0, 1.f, 4);
    gemm(feat0_in, nullptr, WOFF(layer) + 65536, 196608, kb, vb, nullptr,
         4096, 256, 512, 256, 1048576, 2097152, nullptr, 7, 0, 2, 0, 0, 1.f, 4);
    gemm(feat1_in, nullptr, WOFF(layer) + 65536, 196608, kb + 1048576, vb + 1048576, nullptr,
         4096, 256, 512, 256, 1048576, 2097152, nullptr, 7, 0, 2, 0, 0, 1.f, 4);
    encTail(seeds, 100, 8192, layer, 4, nullptr, nullptr, 7, 0);
  };
  auto encFeatLayer = [&](int layer) {
    gemm(f01, nullptr, WOFF(layer), 196608, qb, nullptr, nullptr,
         4096, 256, 256, 256, 1048576, 1048576, nullptr, 7, 0, 2, 0, 0, 1.f, 8);
    gemm(seeds, nullptr, WOFF(layer) + 65536, 196608, kb, vb, nullptr,
         100, 256, 512, 256, 25600, 25600, nullptr, 3, 0, 2, 0, 0, 1.f, 8);
    encTail(f01, 4096, 100, layer, 8, nullptr, nullptr, 7, 0);
  };

  encSeedLayer(0);
  encFeatLayer(1);
  encSeedLayer(2);
  encFeatLayer(3);

  // ---- seeds final + dmatrix ----
  seedsF_kernel<<<dim3(4, 100), 256, 0, stream>>>(seeds, topicp, sF);
  transpose_seeds_kernel<<<400, 256, 0, stream>>>(sF, sT);
  {
    dim3 g(1, 32, 4), blk(256);
    gemm_f32b_kernel<<<g, blk, 0, stream>>>(feat0_in, sT, dmat, 4096, 100, 256, 1048576, 25600, 819200, 0.0625f);
    gemm_f32b_kernel<<<g, blk, 0, stream>>>(feat1_in, sT, dmat + 409600, 4096, 100, 256, 1048576, 25600, 819200, 0.0625f);
  }
  float* prob = kb;
  softmax_rows_kernel<<<32768, 128, 0, stream>>>(dmat, prob);
  colsum_kernel<<<dim3(100, 4, 2), 256, 0, stream>>>(prob, cs0, cs1);
  topk_kernel<<<4, 128, 0, stream>>>(cs0, cs1, inds);
  argmax_rows_kernel<<<128, 256, 0, stream>>>(dmat, amax);

  hipMemsetAsync(up01, 0, 8388608 * sizeof(float), stream);

  // ---- sample loop ----
  for (int kk = 0; kk < 6; kk++) {
    build_ord_kernel<<<dim3(4, 2), 1024, 0, stream>>>(amax, inds, kk, ord8, cnt8);
    cond_kernel<<<1, 1, 0, stream>>>(cnt8, condf);
    gather_kernel<<<dim3(4096, 8), 256, 0, stream>>>(nf, f01, ord8, cnt8);
    for (int idt = 0; idt < 2; idt++) {
      int wA = 4 + idt * 2, wB = wA + 1;
      // wA: self-attention, z=8 batched (shared weights)
      gemm(nf, nullptr, WOFF(wA), 196608, qb, kb, vb,
           4096, 256, 768, 256, 1048576, 1048576, cnt8, 7, 0, 2, 2, 0, 1.f, 8);
      encTail(nf, 4096, 4096, wA, 8, cnt8, cnt8, 7, 0);
      // wB step 1: x = nf[0..3], source = nf[4..7]
      gemm(nf, nullptr, WOFF(wB), 196608, qb, nullptr, nullptr,
           4096, 256, 256, 256, 1048576, 1048576, cnt8, 7, 0, 2, 0, 0, 1.f, 4);
      gemm(nf, nullptr, WOFF(wB) + 65536, 196608, kb, vb, nullptr,
           4096, 256, 512, 256, 1048576, 1048576, cnt8, 7, 4, 2, 0, 0, 1.f, 4);
      encTail(nf, 4096, 4096, wB, 4, cnt8, cnt8, 7, 4);
      // wB step 2: x = nf[4..7], source = UPDATED nf[0..3]
      gemm(nf + 4194304, nullptr, WOFF(wB), 196608, qb, nullptr, nullptr,
           4096, 256, 256, 256, 1048576, 1048576, cnt8 + 4, 7, 0, 2, 0, 0, 1.f, 4);
      gemm(nf, nullptr, WOFF(wB) + 65536, 196608, kb, vb, nullptr,
           4096, 256, 512, 256, 1048576, 1048576, cnt8, 7, 0, 2, 0, 0, 1.f, 4);
      encTail(nf + 4194304, 4096, 4096, wB, 4, cnt8 + 4, cnt8, 7, 0);
    }
    scatter_kernel<<<dim3(4096, 8), 256, 0, stream>>>(up01, nf, ord8, cnt8, condf);
  }

  // ---- outputs ----
  final_mix_kernel<<<dim3(4096, 8), 256, 0, stream>>>(f01, up01, amax, inds);
  tmi_kernel<<<dim3(1600, 4, 2), 256, 0, stream>>>(dmat, out);
}

// Round 6
// 6634.031 us; speedup vs baseline: 3.8275x; 1.3108x over previous
//
#include <hip/hip_runtime.h>
#include <math.h>

// N=4, L=S=4096, C=256, K=100, NHEAD=8, D=32. FP32 I/O.
// Big GEMMs: bf16x3 split MFMA (hi*hi + hi*lo + lo*hi, fp32 acc) ~ fp32 fidelity.
// Sample loop batched into 48 packed segments (6 samples x 8 batch-halves),
// 128-aligned inside an [8][4864]-row arena (sum of per-sample counts <= 4096
// per half since argmax assigns each token to exactly one topic).
// LN fused into GEMM epilogues (gemm256: full 256-col row per block).

typedef __attribute__((ext_vector_type(8))) short short8;
typedef __attribute__((ext_vector_type(4))) float f32x4;

#define ARENA 4864  // rows per g in packed arena (4096 + 6*128 alignment pad)

__device__ __forceinline__ short f2bf(float f) {
  unsigned u = __float_as_uint(f);
  return (short)((u + 0x7FFFu + ((u >> 16) & 1u)) >> 16);
}
__device__ __forceinline__ float bf2f(short s) {
  return __uint_as_float(((unsigned)(unsigned short)s) << 16);
}

// ---------------------------------------------------------------------------
// Weight prep: per layer L, transposed [n][k] bf16 hi/lo planes.
// Per-layer stride 1310720 shorts:
//   +0       QKV [768][256] hi, lo +196608
//   +393216  Wm  [256][256] hi, lo +65536
//   +524288  W1  [512][512] hi, lo +262144
//   +1048576 W2  [256][512] hi, lo +131072
// ---------------------------------------------------------------------------
__global__ void prep_w_kernel(const float* __restrict__ Wq, const float* __restrict__ Wk,
                              const float* __restrict__ Wv, const float* __restrict__ Wm,
                              const float* __restrict__ W1, const float* __restrict__ W2,
                              short* __restrict__ wb) {
  long i = (long)blockIdx.x * 256 + threadIdx.x;
  if (i >= 8L * 655360) return;
  int L = (int)(i / 655360);
  int r = (int)(i % 655360);
  long base = (long)L * 1310720;
  float v; long dhi; int loD;
  if (r < 196608) {
    int n = r >> 8, k = r & 255;
    const float* s = (n < 256) ? (Wq + (long)L * 65536)
                   : (n < 512) ? (Wk + (long)L * 65536) : (Wv + (long)L * 65536);
    v = s[k * 256 + (n & 255)];
    dhi = base + (long)n * 256 + k; loD = 196608;
  } else if (r < 262144) {
    int j = r - 196608; int n = j >> 8, k = j & 255;
    v = Wm[(long)L * 65536 + k * 256 + n];
    dhi = base + 393216 + (long)n * 256 + k; loD = 65536;
  } else if (r < 524288) {
    int j = r - 262144; int n = j >> 9, k = j & 511;
    v = W1[(long)L * 262144 + (long)k * 512 + n];
    dhi = base + 524288 + (long)n * 512 + k; loD = 262144;
  } else {
    int j = r - 524288; int n = j >> 9, k = j & 511;
    v = W2[(long)L * 131072 + (long)k * 256 + n];
    dhi = base + 1048576 + (long)n * 512 + k; loD = 131072;
  }
  short h = f2bf(v);
  wb[dhi] = h;
  wb[dhi + loD] = f2bf(v - bf2f(h));
}

// ---------------------------------------------------------------------------
// gemm_main: 128x128 tiles, plain-batch OR packed-segment addressing,
// up to 3 column-routed outputs, optional dual A ([x | A2] for h1).
// modes: 0 none, 1 relu, 2 elu(x)+1.
// ---------------------------------------------------------------------------
__global__ __launch_bounds__(256) void gemm_main_kernel(
    const float* __restrict__ A, const float* __restrict__ A2, int aw,
    const short* __restrict__ Bh, int loD,
    float* __restrict__ C0, float* __restrict__ C1, float* __restrict__ C2,
    int M, int Kd, int outW, long sA, long sC,
    const int* __restrict__ cnt, int bmask, int bxor,
    const int* __restrict__ segOff, const int* __restrict__ segCnt, int gmin, int gmax,
    int mode0, int mode1, int mode2)
{
  int z = blockIdx.z;
  long aBase, cBase; int cntb;
  if (segOff) {
    int g = z & 7;
    if (g < gmin || g > gmax) return;
    long rb = (long)g * ARENA + segOff[z];
    aBase = rb * aw; cBase = rb * (long)outW;
    cntb = segCnt[z];
  } else {
    int ab = (z & bmask) ^ bxor;
    aBase = (long)ab * sA; cBase = (long)z * sC;
    cntb = cnt ? min(cnt[ab], M) : M;
  }
  int row0 = blockIdx.y * 128;
  if (row0 >= cntb) return;
  int colg = blockIdx.x * 128;
  int sel = colg / outW;
  float* Cb = (sel == 0 ? C0 : (sel == 1 ? C1 : C2)) + cBase;
  int mode = (sel == 0 ? mode0 : (sel == 1 ? mode1 : mode2));
  int colo = colg % outW;

  int t = threadIdx.x;
  int lane = t & 63, wid = t >> 6, wm = wid >> 1, wn = wid & 1;
  int fi = lane & 15, fq = lane >> 4;

  __shared__ __align__(16) short Ah[128][36];
  __shared__ __align__(16) short Al[128][36];
  __shared__ __align__(16) short Bsh[128][36];
  __shared__ __align__(16) short Bsl[128][36];

  f32x4 acc[4][4];
  #pragma unroll
  for (int i = 0; i < 4; i++)
    #pragma unroll
    for (int j = 0; j < 4; j++)
      acc[i][j] = (f32x4){0.f, 0.f, 0.f, 0.f};

  int tr = t >> 3, tc = (t & 7) * 4;
  int nc = t >> 1, kh = (t & 1) * 16;

  for (int k0 = 0; k0 < Kd; k0 += 32) {
    bool useA2 = (A2 != nullptr) && (k0 >= 256);
    const float* Asrc = useA2 ? A2 : A;
    int kcol = useA2 ? (k0 - 256) : k0;
    #pragma unroll
    for (int p = 0; p < 4; p++) {
      int r = tr + p * 32, gr = row0 + r;
      float4 v = make_float4(0.f, 0.f, 0.f, 0.f);
      if (gr < M) v = *(const float4*)&Asrc[aBase + (long)gr * aw + kcol + tc];
      float vv[4] = {v.x, v.y, v.z, v.w};
      #pragma unroll
      for (int e = 0; e < 4; e++) {
        short h = f2bf(vv[e]);
        Ah[r][tc + e] = h;
        Al[r][tc + e] = f2bf(vv[e] - bf2f(h));
      }
    }
    {
      const short* bs = Bh + (long)(colg + nc) * Kd + k0 + kh;
      *(short8*)&Bsh[nc][kh]     = *(const short8*)bs;
      *(short8*)&Bsh[nc][kh + 8] = *(const short8*)(bs + 8);
      *(short8*)&Bsl[nc][kh]     = *(const short8*)(bs + loD);
      *(short8*)&Bsl[nc][kh + 8] = *(const short8*)(bs + loD + 8);
    }
    __syncthreads();
    short8 ah[4], al[4], bh[4], bl[4];
    #pragma unroll
    for (int i = 0; i < 4; i++) {
      ah[i] = *(const short8*)&Ah[wm * 64 + i * 16 + fi][fq * 8];
      al[i] = *(const short8*)&Al[wm * 64 + i * 16 + fi][fq * 8];
    }
    #pragma unroll
    for (int j = 0; j < 4; j++) {
      bh[j] = *(const short8*)&Bsh[wn * 64 + j * 16 + fi][fq * 8];
      bl[j] = *(const short8*)&Bsl[wn * 64 + j * 16 + fi][fq * 8];
    }
    #pragma unroll
    for (int i = 0; i < 4; i++)
      #pragma unroll
      for (int j = 0; j < 4; j++) {
        acc[i][j] = __builtin_amdgcn_mfma_f32_16x16x32_bf16(ah[i], bh[j], acc[i][j], 0, 0, 0);
        acc[i][j] = __builtin_amdgcn_mfma_f32_16x16x32_bf16(ah[i], bl[j], acc[i][j], 0, 0, 0);
        acc[i][j] = __builtin_amdgcn_mfma_f32_16x16x32_bf16(al[i], bh[j], acc[i][j], 0, 0, 0);
      }
    __syncthreads();
  }
  #pragma unroll
  for (int i = 0; i < 4; i++) {
    #pragma unroll
    for (int reg = 0; reg < 4; reg++) {
      int gr = row0 + wm * 64 + i * 16 + fq * 4 + reg;
      if (gr >= M || gr >= cntb) continue;
      #pragma unroll
      for (int j = 0; j < 4; j++) {
        int cc = colo + wn * 64 + j * 16 + fi;
        float v = acc[i][j][reg];
        if (mode == 1) { if (v < 0.f) v = 0.f; }
        else if (mode == 2) { v = (v > 0.f) ? (v + 1.f) : expf(v); }
        Cb[(long)gr * outW + cc] = v;
      }
    }
  }
}

// ---------------------------------------------------------------------------
// gemm256: N=256 exactly, 128x256 tile per block (full output row), plain or
// packed addressing. modes: 0 none, 2 elu+1, 3 LN->C, 4 X += LN (h2+residual).
// ---------------------------------------------------------------------------
__global__ __launch_bounds__(256) void gemm256_kernel(
    const float* __restrict__ A, int aw, const short* __restrict__ Bh, int loD,
    float* __restrict__ C, float* __restrict__ X,
    int M, int Kd, long sA, long sC, long sX,
    const int* __restrict__ cnt, int bmask, int bxor,
    const int* __restrict__ segOff, const int* __restrict__ segCnt, int gmin, int gmax,
    int mode)
{
  int z = blockIdx.z;
  long aBase, cBase, xBase; int cntb;
  if (segOff) {
    int g = z & 7;
    if (g < gmin || g > gmax) return;
    long rb = (long)g * ARENA + segOff[z];
    aBase = rb * aw; cBase = rb * 256; xBase = rb * 256;
    cntb = segCnt[z];
  } else {
    int ab = (z & bmask) ^ bxor;
    aBase = (long)ab * sA; cBase = (long)z * sC; xBase = (long)ab * sX;
    cntb = cnt ? min(cnt[ab], M) : M;
  }
  int row0 = blockIdx.y * 128;
  if (row0 >= cntb) return;

  int t = threadIdx.x;
  int lane = t & 63, wid = t >> 6, wm = wid >> 1, wn = wid & 1;
  int fi = lane & 15, fq = lane >> 4;

  __shared__ __align__(16) short Ah[128][36];
  __shared__ __align__(16) short Al[128][36];
  __shared__ __align__(16) short Bsh[256][36];
  __shared__ __align__(16) short Bsl[256][36];
  __shared__ float lnS[2][128];
  __shared__ float lnQ[2][128];
  __shared__ float muS[128];
  __shared__ float rsS[128];

  f32x4 acc[4][8];
  #pragma unroll
  for (int i = 0; i < 4; i++)
    #pragma unroll
    for (int j = 0; j < 8; j++)
      acc[i][j] = (f32x4){0.f, 0.f, 0.f, 0.f};

  int tr = t >> 3, tc = (t & 7) * 4;

  for (int k0 = 0; k0 < Kd; k0 += 32) {
    #pragma unroll
    for (int p = 0; p < 4; p++) {
      int r = tr + p * 32, gr = row0 + r;
      float4 v = make_float4(0.f, 0.f, 0.f, 0.f);
      if (gr < M) v = *(const float4*)&A[aBase + (long)gr * aw + k0 + tc];
      float vv[4] = {v.x, v.y, v.z, v.w};
      #pragma unroll
      for (int e = 0; e < 4; e++) {
        short h = f2bf(vv[e]);
        Ah[r][tc + e] = h;
        Al[r][tc + e] = f2bf(vv[e] - bf2f(h));
      }
    }
    {
      const short* bs = Bh + (long)t * Kd + k0;
      #pragma unroll
      for (int q = 0; q < 4; q++) {
        *(short8*)&Bsh[t][q * 8] = *(const short8*)(bs + q * 8);
        *(short8*)&Bsl[t][q * 8] = *(const short8*)(bs + loD + q * 8);
      }
    }
    __syncthreads();
    short8 ah[4], al[4];
    #pragma unroll
    for (int i = 0; i < 4; i++) {
      ah[i] = *(const short8*)&Ah[wm * 64 + i * 16 + fi][fq * 8];
      al[i] = *(const short8*)&Al[wm * 64 + i * 16 + fi][fq * 8];
    }
    #pragma unroll
    for (int jh = 0; jh < 2; jh++) {
      short8 bh[4], bl[4];
      #pragma unroll
      for (int j = 0; j < 4; j++) {
        bh[j] = *(const short8*)&Bsh[wn * 128 + (jh * 4 + j) * 16 + fi][fq * 8];
        bl[j] = *(const short8*)&Bsl[wn * 128 + (jh * 4 + j) * 16 + fi][fq * 8];
      }
      #pragma unroll
      for (int i = 0; i < 4; i++)
        #pragma unroll
        for (int j = 0; j < 4; j++) {
          acc[i][jh * 4 + j] = __builtin_amdgcn_mfma_f32_16x16x32_bf16(ah[i], bh[j], acc[i][jh * 4 + j], 0, 0, 0);
          acc[i][jh * 4 + j] = __builtin_amdgcn_mfma_f32_16x16x32_bf16(ah[i], bl[j], acc[i][jh * 4 + j], 0, 0, 0);
          acc[i][jh * 4 + j] = __builtin_amdgcn_mfma_f32_16x16x32_bf16(al[i], bh[j], acc[i][jh * 4 + j], 0, 0, 0);
        }
    }
    __syncthreads();
  }

  if (mode >= 3) {
    // per-row LN stats across all 256 cols
    #pragma unroll
    for (int i = 0; i < 4; i++)
      #pragma unroll
      for (int reg = 0; reg < 4; reg++) {
        float s = 0.f, q = 0.f;
        #pragma unroll
        for (int j = 0; j < 8; j++) { float v = acc[i][j][reg]; s += v; q += v * v; }
        #pragma unroll
        for (int m = 1; m < 16; m <<= 1) { s += __shfl_xor(s, m, 64); q += __shfl_xor(q, m, 64); }
        if (fi == 0) {
          int row = wm * 64 + i * 16 + fq * 4 + reg;
          lnS[wn][row] = s; lnQ[wn][row] = q;
        }
      }
    __syncthreads();
    if (t < 128) {
      float s = lnS[0][t] + lnS[1][t];
      float q = lnQ[0][t] + lnQ[1][t];
      float m = s * (1.f / 256.f);
      float var = q * (1.f / 256.f) - m * m;
      muS[t] = m; rsS[t] = rsqrtf(var + 1e-5f);
    }
    __syncthreads();
  }

  #pragma unroll
  for (int i = 0; i < 4; i++) {
    #pragma unroll
    for (int reg = 0; reg < 4; reg++) {
      int row = wm * 64 + i * 16 + fq * 4 + reg;
      int gr = row0 + row;
      if (gr >= M || gr >= cntb) continue;
      #pragma unroll
      for (int j = 0; j < 8; j++) {
        int col = wn * 128 + j * 16 + fi;
        float v = acc[i][j][reg];
        if (mode == 2) { v = (v > 0.f) ? (v + 1.f) : expf(v); C[cBase + (long)gr * 256 + col] = v; }
        else if (mode == 3) { C[cBase + (long)gr * 256 + col] = (v - muS[row]) * rsS[row]; }
        else if (mode == 4) { X[xBase + (long)gr * 256 + col] += (v - muS[row]) * rsS[row]; }
        else { C[cBase + (long)gr * 256 + col] = v; }
      }
    }
  }
}

// ---------------------------------------------------------------------------
// fp32-B MFMA GEMM (dmatrix only).
// ---------------------------------------------------------------------------
__global__ __launch_bounds__(256) void gemm_f32b_kernel(
    const float* __restrict__ A, const float* __restrict__ B, float* __restrict__ C,
    int M, int N, int Kd, long sA, long sB, long sC, float alpha)
{
  int b = blockIdx.z;
  const float* Ab = A + (long)b * sA;
  const float* Bb = B + (long)b * sB;
  float* Cb = C + (long)b * sC;
  int row0 = blockIdx.y * 128, col0 = blockIdx.x * 128;
  int t = threadIdx.x;
  int lane = t & 63, wid = t >> 6, wm = wid >> 1, wn = wid & 1;
  int fi = lane & 15, fq = lane >> 4;
  __shared__ __align__(16) short Ah[128][36];
  __shared__ __align__(16) short Al[128][36];
  __shared__ __align__(16) short Bsh[128][36];
  __shared__ __align__(16) short Bsl[128][36];
  f32x4 acc[4][4];
  #pragma unroll
  for (int i = 0; i < 4; i++)
    #pragma unroll
    for (int j = 0; j < 4; j++)
      acc[i][j] = (f32x4){0.f, 0.f, 0.f, 0.f};
  int tr = t >> 3, tc = (t & 7) * 4;
  int bn = (t & 31) * 4, bk = t >> 5;
  for (int k0 = 0; k0 < Kd; k0 += 32) {
    #pragma unroll
    for (int p = 0; p < 4; p++) {
      int r = tr + p * 32, gr = row0 + r;
      float4 v = make_float4(0.f, 0.f, 0.f, 0.f);
      if (gr < M) v = *(const float4*)&Ab[(long)gr * Kd + k0 + tc];
      float vv[4] = {v.x, v.y, v.z, v.w};
      #pragma unroll
      for (int e = 0; e < 4; e++) {
        short h = f2bf(vv[e]); Ah[r][tc + e] = h; Al[r][tc + e] = f2bf(vv[e] - bf2f(h));
      }
    }
    #pragma unroll
    for (int p = 0; p < 4; p++) {
      int kk = bk + p * 8;
      long gkN = (long)(k0 + kk) * N;
      #pragma unroll
      for (int e = 0; e < 4; e++) {
        int gc = col0 + bn + e;
        float v = (gc < N) ? Bb[gkN + gc] : 0.f;
        short h = f2bf(v); Bsh[bn + e][kk] = h; Bsl[bn + e][kk] = f2bf(v - bf2f(h));
      }
    }
    __syncthreads();
    short8 ah[4], al[4], bh[4], bl[4];
    #pragma unroll
    for (int i = 0; i < 4; i++) {
      ah[i] = *(const short8*)&Ah[wm * 64 + i * 16 + fi][fq * 8];
      al[i] = *(const short8*)&Al[wm * 64 + i * 16 + fi][fq * 8];
    }
    #pragma unroll
    for (int j = 0; j < 4; j++) {
      bh[j] = *(const short8*)&Bsh[wn * 64 + j * 16 + fi][fq * 8];
      bl[j] = *(const short8*)&Bsl[wn * 64 + j * 16 + fi][fq * 8];
    }
    #pragma unroll
    for (int i = 0; i < 4; i++)
      #pragma unroll
      for (int j = 0; j < 4; j++) {
        acc[i][j] = __builtin_amdgcn_mfma_f32_16x16x32_bf16(ah[i], bh[j], acc[i][j], 0, 0, 0);
        acc[i][j] = __builtin_amdgcn_mfma_f32_16x16x32_bf16(ah[i], bl[j], acc[i][j], 0, 0, 0);
        acc[i][j] = __builtin_amdgcn_mfma_f32_16x16x32_bf16(al[i], bh[j], acc[i][j], 0, 0, 0);
      }
    __syncthreads();
  }
  #pragma unroll
  for (int i = 0; i < 4; i++) {
    #pragma unroll
    for (int reg = 0; reg < 4; reg++) {
      int gr = row0 + wm * 64 + i * 16 + fq * 4 + reg;
      if (gr >= M) continue;
      #pragma unroll
      for (int j = 0; j < 4; j++) {
        int gc = col0 + wn * 64 + j * 16 + fi;
        if (gc < N) Cb[(long)gr * N + gc] = acc[i][j][reg] * alpha;
      }
    }
  }
}

// ---------------------------------------------------------------------------
__device__ __forceinline__ float2 blk_sum2_256(float a, float b)
{
  __shared__ float sa[4], sb[4];
  int lane = threadIdx.x & 63, w = threadIdx.x >> 6;
  #pragma unroll
  for (int off = 32; off > 0; off >>= 1) { a += __shfl_down(a, off, 64); b += __shfl_down(b, off, 64); }
  if (lane == 0) { sa[w] = a; sb[w] = b; }
  __syncthreads();
  float ra = sa[0] + sa[1] + sa[2] + sa[3];
  float rb = sb[0] + sb[1] + sb[2] + sb[3];
  __syncthreads();
  return make_float2(ra, rb);
}

__global__ void cvt_kernel(float* dst, const float* src, long n) {
  long i = (long)blockIdx.x * 256 + threadIdx.x;
  if (i < n) dst[i] = src[i];
}

__global__ void bcast_seeds_kernel(float* seeds, const float* st) {
  long i = (long)blockIdx.x * 256 + threadIdx.x;
  if (i < 4L * 25600) seeds[i] = st[i % 25600];
}

// KV[s,h,d,e] += sum_r K*V*inv_s ; Ksum[s,h,d] += sum_r K. plain or packed.
__global__ __launch_bounds__(1024) void kv_kernel(
    const float* __restrict__ Kb, const float* __restrict__ Vb,
    float* __restrict__ KV, float* __restrict__ Ksum,
    int s_len, float inv_s, const int* __restrict__ cnt, int bmask, int bxor,
    const int* __restrict__ segOff, const int* __restrict__ segCnt,
    int axor, int gmin, int gmax, int chunk)
{
  int s = blockIdx.x, h = blockIdx.y;
  long srcBase; int slim;
  if (segOff) {
    int g = s & 7;
    if (g < gmin || g > gmax) return;
    int src = s ^ axor;
    srcBase = (long)(src & 7) * ARENA + segOff[src];
    slim = segCnt[src];
  } else {
    int ab = (s & bmask) ^ bxor;
    srcBase = (long)s * s_len;
    slim = cnt ? min(cnt[ab], s_len) : s_len;
  }
  int s0b = blockIdx.z * chunk;
  int send = min(s0b + chunk, slim);
  if (s0b >= send) return;
  __shared__ float Kt[32][33];
  __shared__ float Vt[32][33];
  int tx = threadIdx.x, ty = threadIdx.y;
  float acc = 0.f, ks = 0.f;
  for (int s0 = s0b; s0 < send; s0 += 32) {
    int sr = s0 + ty;
    float kvv = 0.f, vvv = 0.f;
    if (sr < send) {
      long base = (srcBase + sr) * 256 + h * 32 + tx;
      kvv = Kb[base]; vvv = Vb[base];
    }
    Kt[ty][tx] = kvv; Vt[ty][tx] = vvv;
    __syncthreads();
    #pragma unroll
    for (int j = 0; j < 32; j++) acc += Kt[j][ty] * Vt[j][tx];
    if (tx == 0) {
      #pragma unroll
      for (int j = 0; j < 32; j++) ks += Kt[j][ty];
    }
    __syncthreads();
  }
  atomicAdd(&KV[((s * 8 + h) * 32 + ty) * 32 + tx], acc * inv_s);
  if (tx == 0) atomicAdd(&Ksum[s * 256 + h * 32 + ty], ks);
}

// msg = (Q·KV) * Z * s_scale ; Z = 1/(Q·Ksum + 1e-6). plain or packed.
__global__ __launch_bounds__(256) void zmsg_kernel(
    const float* __restrict__ Q, const float* __restrict__ KV,
    const float* __restrict__ Ksum, float* __restrict__ msg, int l, float s_scale,
    const int* __restrict__ cnt,
    const int* __restrict__ segOff, const int* __restrict__ segCnt, int gmin, int gmax)
{
  int s = blockIdx.x;
  long rowBase; int cb;
  if (segOff) {
    int g = s & 7;
    if (g < gmin || g > gmax) return;
    rowBase = (long)g * ARENA + segOff[s];
    cb = segCnt[s];
  } else {
    rowBase = (long)s * l;
    cb = cnt ? min(cnt[s], l) : l;
  }
  int r0 = blockIdx.y * 8;
  if (r0 >= cb) return;
  int t = threadIdx.x;
  __shared__ float KVs[8192];
  __shared__ float QL[256];
  __shared__ float Zl[8];
  for (int i = t; i < 8192; i += 256) KVs[i] = KV[s * 8192 + i];
  float Ks = Ksum[s * 256 + t];
  __syncthreads();
  int h = t >> 5, e = t & 31;
  for (int rr = 0; rr < 8; rr++) {
    int row = r0 + rr;
    if (row >= cb) break;
    long base = (rowBase + row) * 256;
    QL[t] = Q[base + t];
    __syncthreads();
    float p = QL[t] * Ks;
    #pragma unroll
    for (int off = 16; off > 0; off >>= 1) p += __shfl_down(p, off, 32);
    if (e == 0) Zl[h] = 1.f / (p + 1e-6f);
    __syncthreads();
    float acc = 0.f;
    const float* kvh = KVs + h * 1024;
    #pragma unroll
    for (int d = 0; d < 32; d++) acc += QL[h * 32 + d] * kvh[d * 32 + e];
    msg[base + t] = acc * Zl[h] * s_scale;
    __syncthreads();
  }
}

// ---------------- topic pipeline ----------------
__global__ void tm_build_kernel(const float* t0, const float* t1, float* tm) {
  int n = blockIdx.x, m = blockIdx.y, l = threadIdx.x;
  if (l >= 100) return;
  float acc = 0.f;
  for (int d = 0; d < 96; d++)
    acc += t0[(n * 96 + d) * 100 + m] * t1[(n * 96 + d) * 100 + l];
  tm[(n * 100 + m) * 100 + l] = floorf(acc * 0.0625f);
}

__global__ void tm_colstats_kernel(const float* tm, float* cmax, float* csum) {
  int n = blockIdx.x, l = blockIdx.y, t = threadIdx.x;
  __shared__ float red[128];
  float v = (t < 100) ? tm[(n * 100 + t) * 100 + l] : -1e30f;
  red[t] = v; __syncthreads();
  for (int off = 64; off > 0; off >>= 1) { if (t < off) red[t] = fmaxf(red[t], red[t + off]); __syncthreads(); }
  float mx = red[0]; __syncthreads();
  float e = (t < 100) ? expf(v - mx) : 0.f;
  red[t] = e; __syncthreads();
  for (int off = 64; off > 0; off >>= 1) { if (t < off) red[t] += red[t + off]; __syncthreads(); }
  if (t == 0) { cmax[n * 100 + l] = mx; csum[n * 100 + l] = red[0]; }
}

__global__ void tm_rowstats_kernel(const float* tm, float* rmax, float* rsum) {
  int n = blockIdx.x, m = blockIdx.y, t = threadIdx.x;
  __shared__ float red[128];
  float v = (t < 100) ? tm[(n * 100 + m) * 100 + t] : -1e30f;
  red[t] = v; __syncthreads();
  for (int off = 64; off > 0; off >>= 1) { if (t < off) red[t] = fmaxf(red[t], red[t + off]); __syncthreads(); }
  float mx = red[0]; __syncthreads();
  float e = (t < 100) ? expf(v - mx) : 0.f;
  red[t] = e; __syncthreads();
  for (int off = 64; off > 0; off >>= 1) { if (t < off) red[t] += red[t + off]; __syncthreads(); }
  if (t == 0) { rmax[n * 100 + m] = mx; rsum[n * 100 + m] = red[0]; }
}

__global__ void tm_argmax_kernel(const float* tm, const float* cmax, const float* csum,
                                 const float* rmax, const float* rsum, int* tmidx) {
  int n = blockIdx.x, m = blockIdx.y, t = threadIdx.x;
  __shared__ float rv[128]; __shared__ int ri[128];
  float v = -1e30f;
  if (t < 100) {
    float x = tm[(n * 100 + m) * 100 + t];
    v = (expf(x - cmax[n * 100 + t]) / csum[n * 100 + t]) * (expf(x - rmax[n * 100 + m]) / rsum[n * 100 + m]);
  }
  rv[t] = v; ri[t] = t; __syncthreads();
  for (int off = 64; off > 0; off >>= 1) {
    if (t < off) {
      if (rv[t + off] > rv[t] || (rv[t + off] == rv[t] && ri[t + off] < ri[t])) { rv[t] = rv[t + off]; ri[t] = ri[t + off]; }
    }
    __syncthreads();
  }
  if (t == 0) tmidx[n * 100 + m] = ri[0];
}

__global__ void topicp_kernel(const float* t0raw, const float* t1raw, const int* tmidx, float* topicp) {
  int n = blockIdx.x, m = blockIdx.y, j = threadIdx.x;
  if (j >= 96) return;
  int g = tmidx[300 + m];
  float a, b;
  if (j < 48) {
    a = t0raw[(n * 96 + 2 * j) * 100 + m];
    b = t0raw[(n * 96 + 2 * j + 1) * 100 + m];
  } else {
    int d0 = 2 * j - 96;
    a = t1raw[(n * 96 + d0) * 100 + g];
    b = t1raw[(n * 96 + d0 + 1) * 100 + g];
  }
  topicp[(n * 100 + m) * 96 + j] = 0.5f * (a + b);
}

__global__ void seedsF_kernel(const float* seeds, const float* topicp, float* seedsF) {
  int n = blockIdx.x, k = blockIdx.y, t = threadIdx.x;
  float v;
  if (t < 160) {
    int s = (t * 256) / 160;
    int e = ((t + 1) * 256 + 159) / 160;
    float a = 0.f;
    for (int i = s; i < e; i++) a += seeds[(n * 100 + k) * 256 + i];
    v = a / (float)(e - s);
  } else {
    v = topicp[(n * 100 + k) * 96 + (t - 160)];
  }
  float2 r = blk_sum2_256(v, v * v);
  float m = r.x * (1.f / 256.f);
  float var = r.y * (1.f / 256.f) - m * m;
  seedsF[(n * 100 + k) * 256 + t] = (v - m) * rsqrtf(var + 1e-5f);
}

__global__ void transpose_seeds_kernel(const float* sF, float* sT) {
  long i = (long)blockIdx.x * 256 + threadIdx.x;
  if (i >= 4L * 25600) return;
  int n = (int)(i / 25600); int r = (int)(i % 25600); int k = r / 256; int d = r % 256;
  sT[n * 25600 + d * 100 + k] = sF[i];
}

// ---------------- dmatrix post ----------------
__global__ void softmax_rows_kernel(const float* dm, float* prob) {
  long row = blockIdx.x; int t = threadIdx.x;
  __shared__ float red[128];
  float v = (t < 100) ? dm[row * 100 + t] : -1e30f;
  red[t] = v; __syncthreads();
  for (int off = 64; off > 0; off >>= 1) { if (t < off) red[t] = fmaxf(red[t], red[t + off]); __syncthreads(); }
  float mx = red[0]; __syncthreads();
  float e = (t < 100) ? expf(v - mx) : 0.f;
  red[t] = e; __syncthreads();
  for (int off = 64; off > 0; off >>= 1) { if (t < off) red[t] += red[t + off]; __syncthreads(); }
  float s = red[0];
  if (t < 100) prob[row * 100 + t] = e / s;
}

__global__ void colsum_kernel(const float* prob, float* cs0, float* cs1) {
  int k = blockIdx.x, n = blockIdx.y, half = blockIdx.z;
  int t = threadIdx.x;
  const float* p = prob + ((long)n * 8192 + half * 4096) * 100 + k;
  float s = 0.f;
  for (int m = t; m < 4096; m += 256) s += p[(long)m * 100];
  float2 r = blk_sum2_256(s, 0.f);
  if (t == 0) (half ? cs1 : cs0)[n * 100 + k] = r.x;
}

__global__ void topk_kernel(const float* cs0, const float* cs1, int* inds) {
  int n = blockIdx.x, t = threadIdx.x;
  __shared__ float rv[128]; __shared__ int ri[128]; __shared__ int sbest;
  float base = (t < 100) ? cs0[n * 100 + t] * cs1[n * 100 + t] : -1.f;
  for (int kk = 0; kk < 6; kk++) {
    rv[t] = base; ri[t] = t; __syncthreads();
    for (int off = 64; off > 0; off >>= 1) {
      if (t < off) {
        if (rv[t + off] > rv[t] || (rv[t + off] == rv[t] && ri[t + off] < ri[t])) { rv[t] = rv[t + off]; ri[t] = ri[t + off]; }
      }
      __syncthreads();
    }
    if (t == 0) { inds[n * 6 + kk] = ri[0]; sbest = ri[0]; }
    __syncthreads();
    if (t == sbest) base = -1.f;
    __syncthreads();
  }
}

__global__ void argmax_rows_kernel(const float* dm, int* amax) {
  int row = blockIdx.x * 256 + threadIdx.x;
  if (row >= 32768) return;
  const float* p = dm + (long)row * 100;
  float best = p[0]; int bi = 0;
  for (int k = 1; k < 100; k++) { float v = p[k]; if (v > best) { best = v; bi = k; } }
  amax[row] = bi;
}

// ---------------- packed sample machinery ----------------
__global__ __launch_bounds__(1024) void count_kernel(const int* amax, const int* inds, int* segCnt) {
  int seg = blockIdx.x;
  int kk = seg >> 3, g = seg & 7, n = g & 3, half = g >> 2;
  int target = inds[n * 6 + kk];
  const int* am = amax + n * 8192 + half * 4096;
  int t = threadIdx.x;
  int lc = 0;
  #pragma unroll
  for (int j = 0; j < 4; j++) lc += (am[t * 4 + j] == target) ? 1 : 0;
  __shared__ int red[16];
  #pragma unroll
  for (int off = 32; off > 0; off >>= 1) lc += __shfl_down(lc, off, 64);
  if ((t & 63) == 0) red[t >> 6] = lc;
  __syncthreads();
  if (t == 0) {
    int s = 0;
    for (int w = 0; w < 16; w++) s += red[w];
    segCnt[seg] = s;
  }
}

__global__ void offs_kernel(const int* segCnt, int* segOff, float* condf) {
  int t = threadIdx.x;
  if (t < 8) {
    int run = 0;
    for (int kk = 0; kk < 6; kk++) {
      segOff[kk * 8 + t] = run;
      run += (segCnt[kk * 8 + t] + 127) & ~127;
    }
  }
  if (t >= 8 && t < 14) {
    int kk = t - 8;
    int a = 0, b = 0;
    for (int g = 0; g < 4; g++) { a += segCnt[kk * 8 + g]; b += segCnt[kk * 8 + 4 + g]; }
    condf[kk] = (a > 0 && b > 0) ? 1.f : 0.f;
  }
}

__global__ __launch_bounds__(1024) void ord_kernel(const int* amax, const int* inds,
                                                   const int* segOff, int* ordP) {
  int seg = blockIdx.x;
  int kk = seg >> 3, g = seg & 7, n = g & 3, half = g >> 2;
  int target = inds[n * 6 + kk];
  const int* am = amax + n * 8192 + half * 4096;
  int t = threadIdx.x;
  __shared__ int ts[1024];
  int f[4]; int lc = 0;
  #pragma unroll
  for (int j = 0; j < 4; j++) { f[j] = (am[t * 4 + j] == target) ? 1 : 0; lc += f[j]; }
  ts[t] = lc; __syncthreads();
  for (int off = 1; off < 1024; off <<= 1) {
    int add = (t >= off) ? ts[t - off] : 0;
    __syncthreads();
    ts[t] += add;
    __syncthreads();
  }
  int run = (t == 0) ? 0 : ts[t - 1];
  int* o = ordP + ((long)g * ARENA + segOff[seg]);
  #pragma unroll
  for (int j = 0; j < 4; j++) {
    if (f[j]) { o[run] = t * 4 + j; run++; }
  }
}

__global__ void gather_kernel(float* nf, const float* f01, const int* ordP,
                              const int* segOff, const int* segCnt) {
  int seg = blockIdx.y;
  int g = seg & 7;
  int cntb = segCnt[seg];
  int row0 = blockIdx.x * 128;
  if (row0 >= cntb) return;
  long base = (long)g * ARENA + segOff[seg];
  int t = threadIdx.x;
  int c4 = (t & 63) * 4, rr = t >> 6;
  for (int p = 0; p < 32; p++) {
    int r = row0 + p * 4 + rr;
    if (r >= cntb) break;
    int tok = ordP[base + r];
    *(float4*)&nf[(base + r) * 256 + c4] =
        *(const float4*)&f01[((long)g * 4096 + tok) * 256 + c4];
  }
}

__global__ void scatter_kernel(float* up, const float* nf, const int* ordP,
                               const int* segOff, const int* segCnt, const float* condf) {
  int seg = blockIdx.y;
  int kk = seg >> 3, g = seg & 7;
  int cntb = segCnt[seg];
  int row0 = blockIdx.x * 128;
  if (row0 >= cntb) return;
  long base = (long)g * ARENA + segOff[seg];
  float cf = condf[kk];
  int t = threadIdx.x;
  int c4 = (t & 63) * 4, rr = t >> 6;
  for (int p = 0; p < 32; p++) {
    int r = row0 + p * 4 + rr;
    if (r >= cntb) break;
    int tok = ordP[base + r];
    float4 add = *(const float4*)&nf[(base + r) * 256 + c4];
    float4* dst = (float4*)&up[((long)g * 4096 + tok) * 256 + c4];
    float4 cur = *dst;
    cur.x += add.x * cf; cur.y += add.y * cf; cur.z += add.z * cf; cur.w += add.w * cf;
    *dst = cur;
  }
}

// up01 aliases out's feat region (index-identical); in-place RMW.
__global__ void final_mix_kernel(const float* f01, float* out_up, const int* amax,
                                 const int* inds) {
  int b = blockIdx.y, half = b >> 2, n = b & 3;
  int l = blockIdx.x, c = threadIdx.x;
  int a = amax[n * 8192 + half * 4096 + l];
  const int* in_ = inds + n * 6;
  bool member = (a == in_[0]) | (a == in_[1]) | (a == in_[2]) | (a == in_[3]) | (a == in_[4]) | (a == in_[5]);
  long idx = ((long)b * 4096 + l) * 256 + c;
  float up = out_up[idx];
  out_up[idx] = (member ? 0.f : 1.f) * f01[idx] + up;
}

__global__ void tmi_kernel(const float* dmat, float* out) {
  int n = blockIdx.y, half = blockIdx.z;
  long i = (long)blockIdx.x * 256 + threadIdx.x;
  const float* dm = dmat + (long)n * 819200 + (long)half * 409600;
  int a = (int)(i / 100), b = (int)(i % 100);
  int y = a >> 6, x = a & 63;
  float sum = 0.f;
  for (int dy = -1; dy <= 1; dy++) {
    int yy = y + dy; if (yy < 0 || yy >= 64) continue;
    for (int dx = -1; dx <= 1; dx++) {
      int xc = x + dx; if (xc < 0 || xc >= 64) continue;
      sum += dm[b * 4096 + yy * 64 + xc];
    }
  }
  out[8388608L + (long)half * 1638400 + (long)n * 409600 + i] = dm[i] * (sum * (1.f / 9.f));
}

// ---------------------------------------------------------------------------
extern "C" void kernel_launch(void* const* d_in, const int* in_sizes, int n_in,
                              void* d_out, int out_size, void* d_ws, size_t ws_size,
                              hipStream_t stream)
{
  (void)in_sizes; (void)n_in; (void)out_size; (void)ws_size;
  const float* feat0_in = (const float*)d_in[0];
  const float* feat1_in = (const float*)d_in[1];
  const float* topic0 = (const float*)d_in[2];
  const float* topic1 = (const float*)d_in[3];
  const float* seed_tokens = (const float*)d_in[4];
  const float* Wq = (const float*)d_in[5];
  const float* Wk = (const float*)d_in[6];
  const float* Wv = (const float*)d_in[7];
  const float* Wm = (const float*)d_in[8];
  const float* W1 = (const float*)d_in[9];
  const float* W2 = (const float*)d_in[10];
  float* out = (float*)d_out;

  float* base = (float*)d_ws;
  long off = 0;
  auto alloc = [&](long n) -> float* { float* p = base + off; off += (n + 255) & ~255L; return p; };
  float* f01   = alloc(8388608);          // [8][4096][256]
  float* qb    = alloc(8L * ARENA * 256); // Q / LN(msg2)
  float* kb    = alloc(8L * ARENA * 256); // K / msg / h1 low   (kb,vb contiguous)
  float* vb    = alloc(8L * ARENA * 256); // V / h1 high
  float* nf    = alloc(8L * ARENA * 256); // packed sample tokens
  float* seeds = alloc(102400);
  float* kvks  = alloc(48 * 8192 + 48 * 256);
  float* dmat  = alloc(3276800);
  short* wbuf  = (short*)alloc(5242880);
  float* tmb   = alloc(40000);
  float* cmaxb = alloc(400); float* csumb = alloc(400);
  float* rmaxb = alloc(400); float* rsumb = alloc(400);
  float* topicp= alloc(38400);
  float* sF    = alloc(102400);
  float* sT    = alloc(102400);
  float* cs0   = alloc(400);
  float* cs1   = alloc(400);
  float* condf = alloc(256);
  int* tmidx  = (int*)alloc(400);
  int* amax   = (int*)alloc(32768);
  int* inds   = (int*)alloc(256);
  int* segCnt = (int*)alloc(256);
  int* segOffA= (int*)alloc(256);
  int* ordP   = (int*)alloc(8L * ARENA);
  float* up01 = out;                      // aliases out's feat region

  auto WOFF = [](int l) -> long { return (long)l * 1310720; };

  auto gmain = [&](const float* A, const float* A2, int aw, long wOff, int loD,
                   float* c0, float* c1, float* c2, int M, int Kd, int Ntot, int outW,
                   long sA_, long sC_, int bm, int bx,
                   const int* sOff, int gmin, int gmax,
                   int m0, int m1, int m2_, int nb) {
    dim3 g(Ntot / 128, (M + 127) / 128, nb), blk(256);
    gemm_main_kernel<<<g, blk, 0, stream>>>(A, A2, aw, wbuf + wOff, loD, c0, c1, c2,
        M, Kd, outW, sA_, sC_, nullptr, bm, bx, sOff, sOff ? segCnt : nullptr, gmin, gmax, m0, m1, m2_);
  };
  auto g256 = [&](const float* A, int aw, long wOff, int loD, float* C, float* X,
                  int M, int Kd, long sA_, long sC_, long sX_, int bm, int bx,
                  const int* sOff, int gmin, int gmax, int mode, int nb) {
    dim3 g(1, (M + 127) / 128, nb), blk(256);
    gemm256_kernel<<<g, blk, 0, stream>>>(A, aw, wbuf + wOff, loD, C, X,
        M, Kd, sA_, sC_, sX_, nullptr, bm, bx, sOff, sOff ? segCnt : nullptr, gmin, gmax, mode);
  };
  // encTail: Q in qb, K in kb, V in vb already. kv -> zmsg(msg->kb) ->
  // msg2+LN -> qb -> h1 -> kbvb[row][512] -> h2+addLN -> x
  auto encTail = [&](float* x, int l, int s_len, float s_scale, int layer, int nb,
                     long sAx, const int* sOff, int gmin, int gmax, int axor, int bmKV, int bxKV) {
    hipMemsetAsync(kvks, 0, (48 * 8192 + 48 * 256) * sizeof(float), stream);
    int nch = (s_len + 1023) / 1024;
    kv_kernel<<<dim3(nb, 8, nch), dim3(32, 32), 0, stream>>>(
        kb, vb, kvks, kvks + 48 * 8192, s_len, 1.f / s_scale, nullptr, bmKV, bxKV,
        sOff, sOff ? segCnt : nullptr, axor, gmin, gmax, 1024);
    zmsg_kernel<<<dim3(nb, (l + 7) / 8), 256, 0, stream>>>(
        qb, kvks, kvks + 48 * 8192, kb, l, s_scale, nullptr,
        sOff, sOff ? segCnt : nullptr, gmin, gmax);
    g256(kb, 256, WOFF(layer) + 393216, 65536, qb, nullptr,
         l, 256, sAx, sAx, 0, 7, 0, sOff, gmin, gmax, 3, nb);
    gmain(x, qb, 256, WOFF(layer) + 524288, 262144, kb, nullptr, nullptr,
          l, 512, 512, 512, sAx, sAx * 2, 7, 0, sOff, gmin, gmax, 1, 0, 0, nb);
    g256(kb, 512, WOFF(layer) + 1048576, 131072, nullptr, x,
         l, 512, sAx * 2, 0, sAx, 7, 0, sOff, gmin, gmax, 4, nb);
  };

  // ---- init ----
  cvt_kernel<<<16384, 256, 0, stream>>>(f01, feat0_in, 4194304);
  cvt_kernel<<<16384, 256, 0, stream>>>(f01 + 4194304, feat1_in, 4194304);
  bcast_seeds_kernel<<<400, 256, 0, stream>>>(seeds, seed_tokens);
  prep_w_kernel<<<20480, 256, 0, stream>>>(Wq, Wk, Wv, Wm, W1, W2, wbuf);

  // ---- topic pipeline ----
  tm_build_kernel<<<dim3(4, 100), 128, 0, stream>>>(topic0, topic1, tmb);
  tm_colstats_kernel<<<dim3(4, 100), 128, 0, stream>>>(tmb, cmaxb, csumb);
  tm_rowstats_kernel<<<dim3(4, 100), 128, 0, stream>>>(tmb, rmaxb, rsumb);
  tm_argmax_kernel<<<dim3(4, 100), 128, 0, stream>>>(tmb, cmaxb, csumb, rmaxb, rsumb, tmidx);
  topicp_kernel<<<dim3(4, 100), 128, 0, stream>>>(topic0, topic1, tmidx, topicp);

  // ---- main encoder layers ----
  auto encSeedLayer = [&](int layer) {
    g256(seeds, 256, WOFF(layer), 196608, qb, nullptr,
         100, 256, 25600, 25600, 0, 7, 0, nullptr, 0, 7, 2, 4);
    gmain(feat0_in, nullptr, 256, WOFF(layer) + 65536, 196608, kb, vb, nullptr,
          4096, 256, 512, 256, 1048576, 2097152, 7, 0, nullptr, 0, 7, 2, 0, 0, 4);
    gmain(feat1_in, nullptr, 256, WOFF(layer) + 65536, 196608, kb + 1048576, vb + 1048576, nullptr,
          4096, 256, 512, 256, 1048576, 2097152, 7, 0, nullptr, 0, 7, 2, 0, 0, 4);
    encTail(seeds, 100, 8192, 8192.f, layer, 4, 25600, nullptr, 0, 7, 0, 7, 0);
  };
  auto encFeatLayer = [&](int layer) {
    g256(f01, 256, WOFF(layer), 196608, qb, nullptr,
         4096, 256, 1048576, 1048576, 0, 7, 0, nullptr, 0, 7, 2, 8);
    gmain(seeds, nullptr, 256, WOFF(layer) + 65536, 196608, kb, vb, nullptr,
          100, 256, 512, 256, 25600, 25600, 3, 0, nullptr, 0, 7, 2, 0, 0, 8);
    encTail(f01, 4096, 100, 100.f, layer, 8, 1048576, nullptr, 0, 7, 0, 7, 0);
  };

  encSeedLayer(0);
  encFeatLayer(1);
  encSeedLayer(2);
  encFeatLayer(3);

  // ---- seeds final + dmatrix ----
  seedsF_kernel<<<dim3(4, 100), 256, 0, stream>>>(seeds, topicp, sF);
  transpose_seeds_kernel<<<400, 256, 0, stream>>>(sF, sT);
  {
    dim3 g(1, 32, 4), blk(256);
    gemm_f32b_kernel<<<g, blk, 0, stream>>>(feat0_in, sT, dmat, 4096, 100, 256, 1048576, 25600, 819200, 0.0625f);
    gemm_f32b_kernel<<<g, blk, 0, stream>>>(feat1_in, sT, dmat + 409600, 4096, 100, 256, 1048576, 25600, 819200, 0.0625f);
  }
  float* prob = kb;
  softmax_rows_kernel<<<32768, 128, 0, stream>>>(dmat, prob);
  colsum_kernel<<<dim3(100, 4, 2), 256, 0, stream>>>(prob, cs0, cs1);
  topk_kernel<<<4, 128, 0, stream>>>(cs0, cs1, inds);
  argmax_rows_kernel<<<128, 256, 0, stream>>>(dmat, amax);

  hipMemsetAsync(up01, 0, 8388608 * sizeof(float), stream);

  // ---- sample phase: all 6 samples x 8 halves packed into 48 segments ----
  count_kernel<<<48, 1024, 0, stream>>>(amax, inds, segCnt);
  offs_kernel<<<1, 64, 0, stream>>>(segCnt, segOffA, condf);
  ord_kernel<<<48, 1024, 0, stream>>>(amax, inds, segOffA, ordP);
  gather_kernel<<<dim3(32, 48), 256, 0, stream>>>(nf, f01, ordP, segOffA, segCnt);

  for (int idt = 0; idt < 2; idt++) {
    int wA = 4 + idt * 2, wB = wA + 1;
    // wA: self-attention, all 48 segments
    gmain(nf, nullptr, 256, WOFF(wA), 196608, qb, kb, vb,
          4096, 256, 768, 256, 0, 0, 0, 0, segOffA, 0, 7, 2, 2, 0, 48);
    encTail(nf, 4096, 4096, 4096.f, wA, 48, 0, segOffA, 0, 7, 0, 0, 0);
    // wB step 1: x = g0..3, source = g4..7
    g256(nf, 256, WOFF(wB), 196608, qb, nullptr,
         4096, 256, 0, 0, 0, 0, 0, segOffA, 0, 3, 2, 48);
    gmain(nf, nullptr, 256, WOFF(wB) + 65536, 196608, kb, vb, nullptr,
          4096, 256, 512, 256, 0, 0, 0, 0, segOffA, 4, 7, 2, 0, 0, 48);
    encTail(nf, 4096, 4096, 4096.f, wB, 48, 0, segOffA, 0, 3, 4, 0, 0);
    // wB step 2: x = g4..7, source = UPDATED g0..3
    g256(nf, 256, WOFF(wB), 196608, qb, nullptr,
         4096, 256, 0, 0, 0, 0, 0, segOffA, 4, 7, 2, 48);
    gmain(nf, nullptr, 256, WOFF(wB) + 65536, 196608, kb, vb, nullptr,
          4096, 256, 512, 256, 0, 0, 0, 0, segOffA, 0, 3, 2, 0, 0, 48);
    encTail(nf, 4096, 4096, 4096.f, wB, 48, 0, segOffA, 4, 7, 4, 0, 0);
  }
  scatter_kernel<<<dim3(32, 48), 256, 0, stream>>>(up01, nf, ordP, segOffA, segCnt, condf);

  // ---- outputs ----
  final_mix_kernel<<<dim3(4096, 8), 256, 0, stream>>>(f01, up01, amax, inds);
  tmi_kernel<<<dim3(1600, 4, 2), 256, 0, stream>>>(dmat, out);
}